// Round 21
// baseline (602.965 us; speedup 1.0000x reference)
//
#include <hip/hip_runtime.h>
#include <stdint.h>

#define EPS 1e-5f
#define SCALE 0.08838834764831845f  /* 1/sqrt(128) */

typedef __bf16 bf16x8 __attribute__((ext_vector_type(8)));
typedef float f32x4 __attribute__((ext_vector_type(4)));
typedef unsigned short u16;
typedef unsigned int u32;
typedef u16 u16x8 __attribute__((ext_vector_type(8)));

__device__ __forceinline__ u16 f2bf(float f) {
  union { float f; u32 u; } x; x.f = f;
  u32 r = x.u + 0x7fffu + ((x.u >> 16) & 1u);
  return (u16)(r >> 16);
}
__device__ __forceinline__ float bf2f(u16 u) {
  union { u32 u; float f; } x; x.u = ((u32)u) << 16; return x.f;
}
__device__ __forceinline__ void glds16(const void* g, void* l) {
  __builtin_amdgcn_global_load_lds((__attribute__((address_space(1))) void*)g,
                                   (__attribute__((address_space(3))) void*)l,
                                   16, 0, 0);
}

// ---------------- f32 -> bf16 convert, up to 8 segments ----------------------
struct F2B8 {
  const float* in[8];
  u16* out[8];
  int n4[8];
};
__global__ __launch_bounds__(256) void f2b_multi(F2B8 j) {
  const int seg = blockIdx.y;
  const int n4 = j.n4[seg];
  const float* __restrict__ in = j.in[seg];
  u16* __restrict__ out = j.out[seg];
  for (int i = blockIdx.x * 256 + threadIdx.x; i < n4; i += gridDim.x * 256) {
    float4 v = ((const float4*)in)[i];
    ((ushort4*)out)[i] = make_ushort4(f2bf(v.x), f2bf(v.y), f2bf(v.z), f2bf(v.w));
  }
}

// ---------------- transpose weight x2: WT[m,n] = W[n,m], f32 -> bf16 ---------
struct WT2 { const float* W[2]; u16* WT[2]; };
__global__ __launch_bounds__(256)
void wtrans2(WT2 g) {
  __shared__ float tile[64][65];
  const float* __restrict__ W = g.W[blockIdx.z];
  u16* __restrict__ WT = g.WT[blockIdx.z];
  const int bx = blockIdx.x, by = blockIdx.y;   // 16 x 16 blocks of 64x64
  const int r = threadIdx.x >> 2, c0 = (threadIdx.x & 3) * 16;
  const float* src = W + (size_t)(by * 64 + r) * 1024 + bx * 64 + c0;
#pragma unroll
  for (int e = 0; e < 16; e += 4) {
    float4 v = *(const float4*)(src + e);
    tile[r][c0 + e] = v.x; tile[r][c0 + e + 1] = v.y;
    tile[r][c0 + e + 2] = v.z; tile[r][c0 + e + 3] = v.w;
  }
  __syncthreads();
  u16* dst = WT + (size_t)(bx * 64 + r) * 1024 + by * 64 + c0;
#pragma unroll
  for (int e = 0; e < 16; e += 4) {
    ushort4 o = make_ushort4(f2bf(tile[c0 + e][r]), f2bf(tile[c0 + e + 1][r]),
                             f2bf(tile[c0 + e + 2][r]), f2bf(tile[c0 + e + 3][r]));
    *(ushort4*)(dst + e) = o;
  }
}

// ---------------- ip GEMM (r14/r16 proven): 128x128, fused cvt+stats ---------
// T14 post-barrier 1-deep prefetch; coalesced A staging (8 lanes per row).
__global__ __launch_bounds__(256)
void gemm_ip(const float* __restrict__ Af, const u16* __restrict__ B,
             u16* __restrict__ Cb, float* __restrict__ ps,
             float* __restrict__ pq, int M, int N, int K) {
  __shared__ u16 sA[128 * 64];
  __shared__ u16 sB[128 * 64];
  const int nwg = (int)(gridDim.x * gridDim.y);
  const int chunk = nwg >> 3;
  int s = blockIdx.y * gridDim.x + blockIdx.x;
  int t = (s & 7) * chunk + (s >> 3);
  const int bn0 = (t & 7) * 128;
  const int bm0 = (t >> 3) * 128;
  const int tid = threadIdx.x;
  const int w = tid >> 6, l = tid & 63;
  const int wr = w >> 1, wc = w & 1;
  const int lr = l & 15, lk = l >> 4;
  const int swz = lr & 7;

  const int srow = tid >> 3;
  const int lslot = tid & 7;
  const int pslot = lslot ^ (srow & 7);
  const float* As = Af + (size_t)(bm0 + srow) * K + lslot * 8;   // linear
  const int scol = pslot << 3;   // B keeps pre-swizzled source
  const u16* Bb = B + (size_t)(bn0 + srow) * K + scol;
  const size_t rstride32 = (size_t)32 * K;

  f32x4 acc[4][4] = {};
  f32x4 pa0[4], pa1[4];
#pragma unroll
  for (int p = 0; p < 4; ++p) {
    const float* sp = As + (size_t)p * 32 * K;
    pa0[p] = *(const f32x4*)(sp);
    pa1[p] = *(const f32x4*)(sp + 4);
  }

  for (int k0 = 0; k0 < K; k0 += 64) {
#pragma unroll
    for (int p = 0; p < 4; ++p)
      glds16(Bb + p * rstride32 + k0, sB + p * 2048 + w * 512);
    // convert prefetched regs -> LDS (swizzled slot)
#pragma unroll
    for (int p = 0; p < 4; ++p) {
      u16x8 o;
      o[0] = f2bf(pa0[p][0]); o[1] = f2bf(pa0[p][1]);
      o[2] = f2bf(pa0[p][2]); o[3] = f2bf(pa0[p][3]);
      o[4] = f2bf(pa1[p][0]); o[5] = f2bf(pa1[p][1]);
      o[6] = f2bf(pa1[p][2]); o[7] = f2bf(pa1[p][3]);
      *(u16x8*)(sA + p * 2048 + srow * 64 + (pslot << 3)) = o;
    }
    __syncthreads();
    // T14 (post-barrier issue): loads overlap the MFMA phase
    if (k0 + 64 < K) {
#pragma unroll
      for (int p = 0; p < 4; ++p) {
        const float* sp = As + (size_t)p * 32 * K + k0 + 64;
        pa0[p] = *(const f32x4*)(sp);
        pa1[p] = *(const f32x4*)(sp + 4);
      }
    }
#pragma unroll
    for (int ks = 0; ks < 2; ++ks) {
      const int off = (((ks << 2) + lk) ^ swz) << 3;
      bf16x8 af[4], bfr[4];
#pragma unroll
      for (int m = 0; m < 4; ++m)
        af[m] = *(const bf16x8*)(sA + (wr * 64 + m * 16 + lr) * 64 + off);
#pragma unroll
      for (int n = 0; n < 4; ++n)
        bfr[n] = *(const bf16x8*)(sB + (wc * 64 + n * 16 + lr) * 64 + off);
#pragma unroll
      for (int m = 0; m < 4; ++m)
#pragma unroll
        for (int n = 0; n < 4; ++n)
          acc[m][n] = __builtin_amdgcn_mfma_f32_16x16x32_bf16(af[m], bfr[n], acc[m][n], 0, 0, 0);
    }
    __syncthreads();
  }

  // C-store
#pragma unroll
  for (int m = 0; m < 4; ++m) {
    const int grow0 = bm0 + wr * 64 + m * 16 + lk * 4;
#pragma unroll
    for (int n = 0; n < 4; ++n) {
      const int gcol = bn0 + wc * 64 + n * 16 + lr;
#pragma unroll
      for (int i = 0; i < 4; ++i)
        Cb[(size_t)(grow0 + i) * N + gcol] = f2bf(acc[m][n][i]);
    }
  }

  // fused column stats (f32 acc)
  float csum[4], csq[4];
#pragma unroll
  for (int n = 0; n < 4; ++n) {
    float s2 = 0.f, q2 = 0.f;
#pragma unroll
    for (int m = 0; m < 4; ++m)
#pragma unroll
      for (int i = 0; i < 4; ++i) {
        const float v = acc[m][n][i];
        s2 += v; q2 += v * v;
      }
    s2 += __shfl_xor(s2, 16, 64); q2 += __shfl_xor(q2, 16, 64);
    s2 += __shfl_xor(s2, 32, 64); q2 += __shfl_xor(q2, 32, 64);
    csum[n] = s2; csq[n] = q2;
  }
  float* cs = (float*)sA;
  float* cq = cs + 256;
  if (lk == 0) {
#pragma unroll
    for (int n = 0; n < 4; ++n) {
      cs[wr * 128 + wc * 64 + n * 16 + lr] = csum[n];
      cq[wr * 128 + wc * 64 + n * 16 + lr] = csq[n];
    }
  }
  __syncthreads();
  if (tid < 128) {
    const size_t o = (size_t)(bm0 >> 7) * 1024 + bn0 + tid;
    ps[o] = cs[tid] + cs[128 + tid];
    pq[o] = cq[tid] + cq[128 + tid];
  }
}

// ---------------- 128x128 bf16 GEMM (BK=64, T1+T2): C=A@B^T (+bias) ----------
__global__ __launch_bounds__(256)
void gemm_bt(const u16* __restrict__ A, const u16* __restrict__ B,
             const float* __restrict__ bias, u16* __restrict__ Cb,
             int M, int N, int K) {
  __shared__ u16 sA[128 * 64];
  __shared__ u16 sB[128 * 64];
  const int nwg = (int)(gridDim.x * gridDim.y);
  const int chunk = nwg >> 3;
  int s = blockIdx.y * gridDim.x + blockIdx.x;
  int t = (s & 7) * chunk + (s >> 3);
  const int bn0 = (t & 7) * 128;
  const int bm0 = (t >> 3) * 128;
  const int tid = threadIdx.x;
  const int w = tid >> 6, l = tid & 63;
  const int wr = w >> 1, wc = w & 1;
  const int lr = l & 15, lk = l >> 4;
  const int swz = lr & 7;

  const int srow = tid >> 3;
  const int scol = ((tid & 7) ^ (srow & 7)) << 3;
  const u16* Ab = A + (size_t)(bm0 + srow) * K + scol;
  const u16* Bb = B + (size_t)(bn0 + srow) * K + scol;
  const size_t rstride32 = (size_t)32 * K;

  f32x4 acc[4][4] = {};

  for (int k0 = 0; k0 < K; k0 += 64) {
#pragma unroll
    for (int p = 0; p < 4; ++p) {
      glds16(Ab + p * rstride32 + k0, sA + p * 2048 + w * 512);
      glds16(Bb + p * rstride32 + k0, sB + p * 2048 + w * 512);
    }
    __syncthreads();
#pragma unroll
    for (int ks = 0; ks < 2; ++ks) {
      const int off = (((ks << 2) + lk) ^ swz) << 3;
      bf16x8 af[4], bfr[4];
#pragma unroll
      for (int m = 0; m < 4; ++m)
        af[m] = *(const bf16x8*)(sA + (wr * 64 + m * 16 + lr) * 64 + off);
#pragma unroll
      for (int n = 0; n < 4; ++n)
        bfr[n] = *(const bf16x8*)(sB + (wc * 64 + n * 16 + lr) * 64 + off);
#pragma unroll
      for (int m = 0; m < 4; ++m)
#pragma unroll
        for (int n = 0; n < 4; ++n)
          acc[m][n] = __builtin_amdgcn_mfma_f32_16x16x32_bf16(af[m], bfr[n], acc[m][n], 0, 0, 0);
    }
    __syncthreads();
  }

#pragma unroll
  for (int m = 0; m < 4; ++m) {
    const int grow0 = bm0 + wr * 64 + m * 16 + lk * 4;
#pragma unroll
    for (int n = 0; n < 4; ++n) {
      const int gcol = bn0 + wc * 64 + n * 16 + lr;
      const float bv = bias ? bias[gcol] : 0.0f;
#pragma unroll
      for (int i = 0; i < 4; ++i) {
        const float v = acc[m][n][i] + bv;
        Cb[(size_t)(grow0 + i) * N + gcol] = f2bf(v);
      }
    }
  }
}

// ---------------- gemm_bt with grid.z selecting 1 of 3 weight sets -----------
struct G3 { const u16* B[3]; const float* bias[3]; u16* C[3]; };
__global__ __launch_bounds__(256)
void gemm_bt_z(const u16* __restrict__ A, G3 g, int M, int N, int K) {
  __shared__ u16 sA[128 * 64];
  __shared__ u16 sB[128 * 64];
  const int z = blockIdx.z;
  const u16* __restrict__ B = g.B[z];
  const float* __restrict__ bias = g.bias[z];
  u16* __restrict__ Cb = g.C[z];
  const int nwg = (int)(gridDim.x * gridDim.y);
  const int chunk = nwg >> 3;
  int s = blockIdx.y * gridDim.x + blockIdx.x;
  int t = (s & 7) * chunk + (s >> 3);
  const int bn0 = (t & 7) * 128;
  const int bm0 = (t >> 3) * 128;
  const int tid = threadIdx.x;
  const int w = tid >> 6, l = tid & 63;
  const int wr = w >> 1, wc = w & 1;
  const int lr = l & 15, lk = l >> 4;
  const int swz = lr & 7;

  const int srow = tid >> 3;
  const int scol = ((tid & 7) ^ (srow & 7)) << 3;
  const u16* Ab = A + (size_t)(bm0 + srow) * K + scol;
  const u16* Bb = B + (size_t)(bn0 + srow) * K + scol;
  const size_t rstride32 = (size_t)32 * K;

  f32x4 acc[4][4] = {};

  for (int k0 = 0; k0 < K; k0 += 64) {
#pragma unroll
    for (int p = 0; p < 4; ++p) {
      glds16(Ab + p * rstride32 + k0, sA + p * 2048 + w * 512);
      glds16(Bb + p * rstride32 + k0, sB + p * 2048 + w * 512);
    }
    __syncthreads();
#pragma unroll
    for (int ks = 0; ks < 2; ++ks) {
      const int off = (((ks << 2) + lk) ^ swz) << 3;
      bf16x8 af[4], bfr[4];
#pragma unroll
      for (int m = 0; m < 4; ++m)
        af[m] = *(const bf16x8*)(sA + (wr * 64 + m * 16 + lr) * 64 + off);
#pragma unroll
      for (int n = 0; n < 4; ++n)
        bfr[n] = *(const bf16x8*)(sB + (wc * 64 + n * 16 + lr) * 64 + off);
#pragma unroll
      for (int m = 0; m < 4; ++m)
#pragma unroll
        for (int n = 0; n < 4; ++n)
          acc[m][n] = __builtin_amdgcn_mfma_f32_16x16x32_bf16(af[m], bfr[n], acc[m][n], 0, 0, 0);
    }
    __syncthreads();
  }

#pragma unroll
  for (int m = 0; m < 4; ++m) {
    const int grow0 = bm0 + wr * 64 + m * 16 + lk * 4;
#pragma unroll
    for (int n = 0; n < 4; ++n) {
      const int gcol = bn0 + wc * 64 + n * 16 + lr;
      const float bv = bias[gcol];
#pragma unroll
      for (int i = 0; i < 4; ++i)
        Cb[(size_t)(grow0 + i) * N + gcol] = f2bf(acc[m][n][i] + bv);
    }
  }
}

// ---------------- q'' GEMM: Q2[b*512+h*64+i, m] = (QV[:,hs]@WT[:,hs]^T)*a[m] -
__global__ __launch_bounds__(256)
void gemm_qpp(const u16* __restrict__ QV, const u16* __restrict__ WT,
              const float* __restrict__ afv, u16* __restrict__ Q2) {
  __shared__ u16 sA[128 * 64];
  __shared__ u16 sB[128 * 64];
  const int h = blockIdx.z;
  int s = blockIdx.y * 8 + blockIdx.x;
  int t = (s & 7) * 16 + (s >> 3);
  const int bn0 = (t & 7) * 128;
  const int bm0 = (t >> 3) * 128;
  const int tid = threadIdx.x;
  const int w = tid >> 6, l = tid & 63;
  const int wr = w >> 1, wc = w & 1;
  const int lr = l & 15, lk = l >> 4;
  const int swz = lr & 7;

  const int srow = tid >> 3;
  const int scol = ((tid & 7) ^ (srow & 7)) << 3;
  const u16* Ab = QV + (size_t)(bm0 + srow) * 1024 + h * 128 + scol;
  const u16* Bb = WT + (size_t)(bn0 + srow) * 1024 + h * 128 + scol;
  const size_t rstride32 = (size_t)32 * 1024;

  f32x4 acc[4][4] = {};

  for (int k0 = 0; k0 < 128; k0 += 64) {
#pragma unroll
    for (int p = 0; p < 4; ++p) {
      glds16(Ab + p * rstride32 + k0, sA + p * 2048 + w * 512);
      glds16(Bb + p * rstride32 + k0, sB + p * 2048 + w * 512);
    }
    __syncthreads();
#pragma unroll
    for (int ks = 0; ks < 2; ++ks) {
      const int off = (((ks << 2) + lk) ^ swz) << 3;
      bf16x8 af[4], bfr[4];
#pragma unroll
      for (int m = 0; m < 4; ++m)
        af[m] = *(const bf16x8*)(sA + (wr * 64 + m * 16 + lr) * 64 + off);
#pragma unroll
      for (int n = 0; n < 4; ++n)
        bfr[n] = *(const bf16x8*)(sB + (wc * 64 + n * 16 + lr) * 64 + off);
#pragma unroll
      for (int m = 0; m < 4; ++m)
#pragma unroll
        for (int n = 0; n < 4; ++n)
          acc[m][n] = __builtin_amdgcn_mfma_f32_16x16x32_bf16(af[m], bfr[n], acc[m][n], 0, 0, 0);
    }
    __syncthreads();
  }

#pragma unroll
  for (int m = 0; m < 4; ++m) {
    const int grow0 = bm0 + wr * 64 + m * 16 + lk * 4;
#pragma unroll
    for (int n = 0; n < 4; ++n) {
      const int gcol = bn0 + wc * 64 + n * 16 + lr;
      const float a = afv[gcol];
#pragma unroll
      for (int i = 0; i < 4; ++i) {
        const int gr = grow0 + i;
        const int q2row = ((gr >> 6) << 9) + h * 64 + (gr & 63);
        Q2[(size_t)q2row * 1024 + gcol] = f2bf(acc[m][n][i] * a);
      }
    }
  }
}

// ---------------- fused vl score + softmax v4: + in-block cst ----------------
// Each block covers ONE head (h = r0>>6), so its 64 cst values (q·wcv dots)
// are computed in-block (8 lanes/row, shuffle-reduce) -- cst_kernel removed.
__global__ __launch_bounds__(512)
void vl_fused(const u16* __restrict__ Q2, const u16* __restrict__ Y1,
              const u16* __restrict__ QV, const float* __restrict__ wcv,
              const float* __restrict__ qmask, float* __restrict__ out) {
  __shared__ u16 sA[2 * 8192];       // 2 x (64 rows x 128 cols) bf16
  __shared__ float redmx[64][8];
  __shared__ float redsm[64][8];
  __shared__ float cst_s[64];
  const int blk = blockIdx.x;       // 256
  const int xcd = blk & 7;
  const int idx = blk >> 3;         // 0..31
  const int b = xcd + 8 * (idx >> 3);
  const int r0 = (idx & 7) * 64;    // row base within b's 512
  const int h = r0 >> 6;            // single head per block
  const int tid = threadIdx.x;
  const int w = tid >> 6, l = tid & 63;
  const int lr = l & 15, lk = l >> 4;

  const int arow0 = tid >> 4;             // 0..31
  const int aslot = tid & 15;
  const u16* Asrc0 = Q2 + (size_t)(b * 512 + r0 + arow0) * 1024 +
                     ((aslot ^ (arow0 & 7)) << 3);
  const u16* Asrc1 = Q2 + (size_t)(b * 512 + 32 + r0 + arow0) * 1024 +
                     ((aslot ^ ((32 + arow0) & 7)) << 3);
  const u16* Brow = Y1 + (size_t)b * 1048576 + (size_t)(w * 128 + lr) * 1024 + lk * 8;

  f32x4 acc[4][8] = {};

  // prologue: stage chunk 0 into buf 0
  glds16(Asrc0, sA + w * 512);
  glds16(Asrc1, sA + 4096 + w * 512);

  // in-block cst: cst_s[j] = QV[b*64+j][h*128:+128] . wcv[h*128:+128]
  {
    const int j = tid >> 3, t8 = tid & 7;
    const u16* qp = QV + (size_t)(b * 64 + j) * 1024 + h * 128 + t8 * 16;
    const float* wp_ = wcv + h * 128 + t8 * 16;
    u16x8 v0 = *(const u16x8*)(qp);
    u16x8 v1 = *(const u16x8*)(qp + 8);
    float sacc = 0.f;
#pragma unroll
    for (int e = 0; e < 8; ++e) sacc += bf2f(v0[e]) * wp_[e];
#pragma unroll
    for (int e = 0; e < 8; ++e) sacc += bf2f(v1[e]) * wp_[8 + e];
    sacc += __shfl_xor(sacc, 1, 64);
    sacc += __shfl_xor(sacc, 2, 64);
    sacc += __shfl_xor(sacc, 4, 64);
    if (t8 == 0) cst_s[j] = sacc;
  }

  for (int c = 0; c < 8; ++c) {
    __syncthreads();                       // buf[c] ready; prev reads done
    const u16* sAc = sA + (c & 1) * 8192;
    if (c < 7) {                           // stage next chunk into other buf
      const int k1 = (c + 1) * 128;
      u16* d = sA + ((c + 1) & 1) * 8192;
      glds16(Asrc0 + k1, d + w * 512);
      glds16(Asrc1 + k1, d + 4096 + w * 512);
    }
    const int k0 = c * 128;
#pragma unroll
    for (int ks = 0; ks < 4; ++ks) {
      bf16x8 af[4];
#pragma unroll
      for (int m = 0; m < 4; ++m) {
        const int row = m * 16 + lr;
        af[m] = *(const bf16x8*)(sAc + row * 128 + ((((ks << 2) + lk) ^ (lr & 7)) << 3));
      }
      const int kc = k0 + (ks << 5);
#pragma unroll
      for (int n = 0; n < 8; ++n) {
        bf16x8 bf_ = *(const bf16x8*)(Brow + (size_t)n * 16384 + kc);
#pragma unroll
        for (int m = 0; m < 4; ++m)
          acc[m][n] = __builtin_amdgcn_mfma_f32_16x16x32_bf16(af[m], bf_, acc[m][n], 0, 0, 0);
      }
    }
  }

  float cst_r[4][4], scl[4][4];
#pragma unroll
  for (int m = 0; m < 4; ++m)
#pragma unroll
    for (int i = 0; i < 4; ++i) {
      const int rl = m * 16 + lk * 4 + i;   // = rem - r0 = rem & 63
      cst_r[m][i] = cst_s[rl];
      scl[m][i] = qmask[b * 64 + rl] * SCALE;
    }
#pragma unroll
  for (int m = 0; m < 4; ++m)
#pragma unroll
    for (int n = 0; n < 8; ++n)
#pragma unroll
      for (int i = 0; i < 4; ++i)
        acc[m][n][i] = (acc[m][n][i] + cst_r[m][i]) * scl[m][i];

  float mx[4][4];
#pragma unroll
  for (int m = 0; m < 4; ++m)
#pragma unroll
    for (int i = 0; i < 4; ++i) {
      float v = -3.4e38f;
#pragma unroll
      for (int n = 0; n < 8; ++n) v = fmaxf(v, acc[m][n][i]);
      for (int o = 1; o < 16; o <<= 1) v = fmaxf(v, __shfl_xor(v, o, 64));
      mx[m][i] = v;
    }
  if (lr == 0) {
#pragma unroll
    for (int m = 0; m < 4; ++m)
#pragma unroll
      for (int i = 0; i < 4; ++i)
        redmx[m * 16 + lk * 4 + i][w] = mx[m][i];
  }
  __syncthreads();
#pragma unroll
  for (int m = 0; m < 4; ++m)
#pragma unroll
    for (int i = 0; i < 4; ++i) {
      const int rl = m * 16 + lk * 4 + i;
      float v = redmx[rl][0];
#pragma unroll
      for (int ww = 1; ww < 8; ++ww) v = fmaxf(v, redmx[rl][ww]);
      mx[m][i] = v;
    }

  float sm[4][4];
#pragma unroll
  for (int m = 0; m < 4; ++m)
#pragma unroll
    for (int i = 0; i < 4; ++i) {
      float s = 0.f;
#pragma unroll
      for (int n = 0; n < 8; ++n) {
        float e = expf(acc[m][n][i] - mx[m][i]);
        acc[m][n][i] = e;
        s += e;
      }
      for (int o = 1; o < 16; o <<= 1) s += __shfl_xor(s, o, 64);
      sm[m][i] = s;
    }
  if (lr == 0) {
#pragma unroll
    for (int m = 0; m < 4; ++m)
#pragma unroll
      for (int i = 0; i < 4; ++i)
        redsm[m * 16 + lk * 4 + i][w] = sm[m][i];
  }
  __syncthreads();
#pragma unroll
  for (int m = 0; m < 4; ++m)
#pragma unroll
    for (int i = 0; i < 4; ++i) {
      const int rl = m * 16 + lk * 4 + i;
      float s = 0.f;
#pragma unroll
      for (int ww = 0; ww < 8; ++ww) s += redsm[rl][ww];
      sm[m][i] = 1.0f / s;
    }

#pragma unroll
  for (int m = 0; m < 4; ++m)
#pragma unroll
    for (int i = 0; i < 4; ++i) {
      const size_t grow = (size_t)(b * 512 + r0 + m * 16 + lk * 4 + i);
#pragma unroll
      for (int n = 0; n < 8; ++n)
        out[grow * 1024 + w * 128 + n * 16 + lr] = acc[m][n][i] * sm[m][i];
    }
}

// ---------------- reduce 256 chunks -> stats + BN-fold vectors a, c ----------
__global__ __launch_bounds__(256)
void colstats_final(const float* __restrict__ ps, const float* __restrict__ pq,
                    float2* __restrict__ st, const float* __restrict__ g,
                    const float* __restrict__ be, float* __restrict__ afv,
                    float* __restrict__ cfv, float inv_n) {
  __shared__ float rs_[8][32], rq_[8][32];
  const int cg = threadIdx.x >> 5, cl = threadIdx.x & 31;
  const int col = blockIdx.x * 32 + cl;
  float s = 0.f, q = 0.f;
  for (int i = 0; i < 32; ++i) {
    const size_t idx = (size_t)(cg * 32 + i) * 1024 + col;
    s += ps[idx]; q += pq[idx];
  }
  rs_[cg][cl] = s; rq_[cg][cl] = q;
  __syncthreads();
  if (cg == 0) {
    for (int i = 1; i < 8; ++i) { s += rs_[i][cl]; q += rq_[i][cl]; }
    const float m = s * inv_n;
    const float v = q * inv_n - m * m;
    const float rs = rsqrtf(v + EPS);
    st[col] = make_float2(m, rs);
    if (afv) {
      const float a = rs * g[col];
      afv[col] = a;
      cfv[col] = be[col] - m * a;
    }
  }
}

// ---------------- small f32 GEMM: out[m,n] = A[m,:]·W[n,:] + bias[n] ---------
__global__ __launch_bounds__(256)
void small_gemm(const float* __restrict__ A, const float* __restrict__ W,
                const float* __restrict__ bias, float* __restrict__ out,
                int N, int K) {
  __shared__ float sA[1024];
  const int m = blockIdx.y;
  const int n = blockIdx.x * 256 + threadIdx.x;
  for (int i = threadIdx.x; i < K; i += 256) sA[i] = A[(size_t)m * K + i];
  __syncthreads();
  const float4* w4 = (const float4*)(W + (size_t)n * K);
  const float4* a4 = (const float4*)sA;
  float acc = bias ? bias[n] : 0.0f;
  for (int k = 0; k < K / 4; ++k) {
    float4 wv = w4[k], av = a4[k];
    acc += av.x * wv.x + av.y * wv.y + av.z * wv.z + av.w * wv.w;
  }
  out[(size_t)m * N + n] = acc;
}

// ---------------- small f32 GEMM, grid.z selects 1 of 2 sets -----------------
struct SG2 { const float* W[2]; const float* bias[2]; float* out[2]; };
__global__ __launch_bounds__(256)
void small_gemm2(const float* __restrict__ A, SG2 g, int N, int K) {
  __shared__ float sA[1024];
  const int z = blockIdx.z;
  const int m = blockIdx.y;
  const int n = blockIdx.x * 256 + threadIdx.x;
  for (int i = threadIdx.x; i < K; i += 256) sA[i] = A[(size_t)m * K + i];
  __syncthreads();
  const float4* w4 = (const float4*)(g.W[z] + (size_t)n * K);
  const float4* a4 = (const float4*)sA;
  float acc = g.bias[z][n];
  for (int k = 0; k < K / 4; ++k) {
    float4 wv = w4[k], av = a4[k];
    acc += av.x * wv.x + av.y * wv.y + av.z * wv.z + av.w * wv.w;
  }
  g.out[z][(size_t)m * N + n] = acc;
}

// ---------------- 1-row vec GEMM x2: out[n] = A·W[n,:] + b[n], 8 thr/output --
struct VG2 { const float* A[2]; const float* W[2]; const float* bias[2]; float* out[2]; };
__global__ __launch_bounds__(256)
void vec_gemm2(VG2 g) {
  __shared__ float sAv[1024];
  const int z = blockIdx.z;
  const float* __restrict__ A = g.A[z];
  const float* __restrict__ W = g.W[z];
  const int tid = threadIdx.x;
  ((float4*)sAv)[tid] = ((const float4*)A)[tid];
  __syncthreads();
  const int og = tid >> 3, t8 = tid & 7;
  const int n = blockIdx.x * 32 + og;
  const float* wr = W + (size_t)n * 1024;
  float s = 0.f;
#pragma unroll
  for (int j = 0; j < 32; ++j) {
    const int k = j * 32 + t8 * 4;
    float4 wv = *(const float4*)(wr + k);
    float4 av = *(const float4*)(sAv + k);
    s += av.x * wv.x + av.y * wv.y + av.z * wv.z + av.w * wv.w;
  }
  s += __shfl_xor(s, 1, 64);
  s += __shfl_xor(s, 2, 64);
  s += __shfl_xor(s, 4, 64);
  if (t8 == 0) g.out[z][n] = s + g.bias[z][n];
}

// ---------------- memory-fuse attention (per batch) --------------------------
__global__ __launch_bounds__(256)
void mem_attn(const float* __restrict__ qmf, const u16* __restrict__ KM,
              const u16* __restrict__ VM, const float* __restrict__ mask,
              float* __restrict__ att_out, float* __restrict__ attv_out) {
  __shared__ float qs[1024];
  __shared__ float sS[512];
  __shared__ float sP[512];
  __shared__ float sM[64];
  const int b = blockIdx.x;
  const int tid = threadIdx.x;
  for (int i = tid; i < 1024; i += 256) qs[i] = qmf[i];
  if (tid < 64) sM[tid] = mask[b * 64 + tid];
  __syncthreads();
  for (int p = tid; p < 512; p += 256) {
    const int h = p >> 6, j = p & 63;
    const u16* kr = KM + (size_t)(b * 64 + j) * 1024 + h * 128;
    float acc = 0.f;
    for (int d = 0; d < 128; ++d) acc += qs[h * 128 + d] * bf2f(kr[d]);
    sS[p] = acc * sM[j] * SCALE;
  }
  __syncthreads();
  if (tid < 8) {
    const int h = tid;
    float mx = -3.4e38f;
    for (int j = 0; j < 64; ++j) mx = fmaxf(mx, sS[h * 64 + j]);
    float sum = 0.f;
    for (int j = 0; j < 64; ++j) {
      float e = expf(sS[h * 64 + j] - mx);
      sP[h * 64 + j] = e; sum += e;
    }
    const float inv = 1.0f / sum;
    for (int j = 0; j < 64; ++j) {
      float pp = sP[h * 64 + j] * inv;
      sP[h * 64 + j] = pp;
      att_out[(size_t)(b * 8 + h) * 64 + j] = pp;
    }
  }
  __syncthreads();
  for (int c = tid; c < 1024; c += 256) {
    const int h = c >> 7;
    float acc = 0.f;
    for (int j = 0; j < 64; ++j)
      acc += sP[h * 64 + j] * sM[j] * bf2f(VM[(size_t)(b * 64 + j) * 1024 + c]);
    attv_out[(size_t)b * 1024 + c] = acc;
  }
}

// ---------------- cur = inorm(concat(neg_tok, mem_out)) ----------------------
__global__ __launch_bounds__(256)
void make_cur(const float* __restrict__ neg, const float* __restrict__ memo,
              float* __restrict__ cur_out, float* __restrict__ curw) {
  const int i = blockIdx.x * 256 + threadIdx.x;   // 32768
  const int b = i >> 10, c = i & 1023;
  const float a = neg[c], x = memo[i];
  const float mean = 0.5f * (a + x);
  const float d = a - mean;
  const float rs = rsqrtf(d * d + EPS);
  const float o0 = d * rs, o1 = -d * rs;
  cur_out[(size_t)(b * 2) * 1024 + c] = o0;
  cur_out[(size_t)(b * 2 + 1) * 1024 + c] = o1;
  curw[(size_t)(b * 2) * 1024 + c] = o0;
  curw[(size_t)(b * 2 + 1) * 1024 + c] = o1;
}

// ---------------- ff fold: w''[b,j,h,:] and const_ff[b,j,h] ------------------
__global__ __launch_bounds__(256)
void ffw_fold(const float* __restrict__ kff, const float* __restrict__ wfq,
              const float* __restrict__ qb, const float* __restrict__ afv,
              const float* __restrict__ cfv, u16* __restrict__ w2ff,
              float* __restrict__ cff) {
  __shared__ float redl[4];
  const int b = blockIdx.y, jh = blockIdx.x;
  const int j = jh >> 3, h = jh & 7;
  const int tid = threadIdx.x;
  const int m0 = tid * 4;
  const float* kp = kff + (size_t)b * 2048 + j * 1024 + h * 128;
  float a0 = 0, a1 = 0, a2 = 0, a3 = 0;
  for (int n = 0; n < 128; ++n) {
    const float kv = kp[n];
    const float4 wv = *(const float4*)(wfq + (size_t)(h * 128 + n) * 1024 + m0);
    a0 += kv * wv.x; a1 += kv * wv.y; a2 += kv * wv.z; a3 += kv * wv.w;
  }
  float cpart = a0 * cfv[m0] + a1 * cfv[m0 + 1] + a2 * cfv[m0 + 2] + a3 * cfv[m0 + 3];
  if (tid < 128) cpart += qb[h * 128 + tid] * kp[tid];
  ushort4 o = make_ushort4(f2bf(a0 * afv[m0]), f2bf(a1 * afv[m0 + 1]),
                           f2bf(a2 * afv[m0 + 2]), f2bf(a3 * afv[m0 + 3]));
  *(ushort4*)(w2ff + (size_t)(b * 16 + jh) * 1024 + m0) = o;
  for (int o2 = 32; o2 > 0; o2 >>= 1) cpart += __shfl_xor(cpart, o2, 64);
  if ((tid & 63) == 0) redl[tid >> 6] = cpart;
  __syncthreads();
  if (tid == 0) cff[b * 16 + jh] = redl[0] + redl[1] + redl[2] + redl[3];
}

// ---------------- ff score v2: reg-direct A (no reuse => no staging) ---------
__global__ __launch_bounds__(256)
void ff_score(const u16* __restrict__ Y1, const u16* __restrict__ w2ff,
              const float* __restrict__ cff, float* __restrict__ P,
              float* __restrict__ att_out) {
  __shared__ u16 sB[16 * 1024];
  const int chunk = blockIdx.x, b = blockIdx.y;
  const int tid = threadIdx.x;
  const int w = tid >> 6, l = tid & 63;
  const int lr = l & 15, lk = l >> 4;
  const int swz = lr & 7;

  {
    const int n = tid >> 4;
    const int sb = (tid & 15) * 8;
#pragma unroll
    for (int v = 0; v < 8; ++v) {
      const int sidx = sb + v;
      u16x8 val = *(const u16x8*)(w2ff + (size_t)(b * 16 + n) * 1024 + sidx * 8);
      *(u16x8*)(sB + n * 1024 + ((sidx ^ (n & 7)) << 3)) = val;
    }
  }
  __syncthreads();

  const u16* Ar = Y1 + ((size_t)(b * 1024 + chunk * 128) + w * 32 + lr) * 1024 + lk * 8;
  f32x4 acc[2] = {};
#pragma unroll 4
  for (int k0 = 0; k0 < 1024; k0 += 32) {
    bf16x8 a0 = *(const bf16x8*)(Ar + k0);
    bf16x8 a1 = *(const bf16x8*)(Ar + 16 * 1024 + k0);
    const int bs = (k0 >> 3) + lk;
    bf16x8 bf_ = *(const bf16x8*)(sB + lr * 1024 + ((bs ^ swz) << 3));
    acc[0] = __builtin_amdgcn_mfma_f32_16x16x32_bf16(a0, bf_, acc[0], 0, 0, 0);
    acc[1] = __builtin_amdgcn_mfma_f32_16x16x32_bf16(a1, bf_, acc[1], 0, 0, 0);
  }

  const float cadd = cff[b * 16 + lr];
  const int h = lr & 7, jj = lr >> 3;
#pragma unroll
  for (int m = 0; m < 2; ++m)
#pragma unroll
    for (int i = 0; i < 4; ++i) {
      const float sval = (acc[m][i] + cadd) * SCALE;
      const float other = __shfl_xor(sval, 8, 64);
      const float mx = fmaxf(sval, other);
      const float e0 = expf(sval - mx), e1 = expf(other - mx);
      const float p = e0 / (e0 + e1);
      const int trow = chunk * 128 + w * 32 + m * 16 + lk * 4 + i;
      P[((size_t)b * 1024 + trow) * 16 + lr] = p;
      att_out[((size_t)(b * 8 + h) * 1024 + trow) * 2 + jj] = p;
    }
}

// ---------------- pbar/G partials: grid (32 b, 8 chunks) ---------------------
__global__ __launch_bounds__(256)
void pg_part(const float* __restrict__ P, float* __restrict__ Gp,
             float* __restrict__ pbarp) {
  __shared__ float Pl[128][16];
  const int b = blockIdx.x, c = blockIdx.y;
  const int tid = threadIdx.x;
  const int j = tid >> 4, j2 = tid & 15;
  for (int i = tid; i < 2048; i += 256)
    Pl[i >> 4][i & 15] = P[((size_t)b * 1024 + c * 128 + (i >> 4)) * 16 + (i & 15)];
  __syncthreads();
  float acc = 0.f, accp = 0.f;
  for (int t = 0; t < 128; ++t) {
    acc += Pl[t][j] * Pl[t][j2];
    if (j == 0) accp += Pl[t][j2];
  }
  Gp[(size_t)(b * 8 + c) * 256 + tid] = acc;
  if (j == 0) pbarp[(b * 8 + c) * 16 + j2] = accp;
}

// ---------------- U[b][jh][m] = sum_d vff[b,j,h*128+d] * wfo[m,h*128+d] ------
__global__ __launch_bounds__(256)
void ufold(const float* __restrict__ vff, const u16* __restrict__ wfoT,
           float* __restrict__ U) {
  const int b = blockIdx.y, jh = blockIdx.x;
  const int j = jh >> 3, h = jh & 7;
  const int m0 = threadIdx.x * 4;
  const float* vp = vff + (size_t)b * 2048 + j * 1024 + h * 128;
  float a0 = 0, a1 = 0, a2 = 0, a3 = 0;
  for (int d = 0; d < 128; ++d) {
    const float kv = vp[d];
    ushort4 wv = *(const ushort4*)(wfoT + (size_t)(h * 128 + d) * 1024 + m0);
    a0 += kv * bf2f(wv.x); a1 += kv * bf2f(wv.y);
    a2 += kv * bf2f(wv.z); a3 += kv * bf2f(wv.w);
  }
  *(float4*)(U + (size_t)(b * 16 + jh) * 1024 + m0) = make_float4(a0, a1, a2, a3);
}

// ---------------- merged: pg-final + analytic inorm stats + U2b prep ---------
// Reduces Gpart/pbarp partials itself (pg_fin removed), writes G/pbar for
// znstats_part, then does the analytic inorm + U2b prep as before.
__global__ __launch_bounds__(256)
void iprep(const float* __restrict__ U, const float* __restrict__ Gp,
           const float* __restrict__ pbp, const float* __restrict__ ob,
           u16* __restrict__ U2b, float* __restrict__ G,
           float* __restrict__ pbar) {
  __shared__ float Gs[256], pb[16];
  const int b = blockIdx.x;
  const int tid = threadIdx.x;
  {
    float s = 0.f;
#pragma unroll
    for (int c = 0; c < 8; ++c) s += Gp[(size_t)(b * 8 + c) * 256 + tid];
    s *= (1.f / 1024.f);
    Gs[tid] = s;
    G[b * 256 + tid] = s;
    if (tid < 16) {
      float p = 0.f;
#pragma unroll
      for (int c = 0; c < 8; ++c) p += pbp[(b * 8 + c) * 16 + tid];
      p *= (1.f / 1024.f);
      pb[tid] = p;
      pbar[b * 16 + tid] = p;
    }
  }
  __syncthreads();
  const int m0 = tid * 4;
  float rr[4], mi4[4];
#pragma unroll
  for (int e = 0; e < 4; ++e) {
    const int m = m0 + e;
    float u[16];
#pragma unroll
    for (int jj = 0; jj < 16; ++jj) u[jj] = U[(size_t)(b * 16 + jj) * 1024 + m];
    const float o = ob[m];
    float s1 = 0.f;
#pragma unroll
    for (int jj = 0; jj < 16; ++jj) s1 += pb[jj] * u[jj];
    float q = 0.f;
#pragma unroll
    for (int jj = 0; jj < 16; ++jj) {
      float gq = 0.f;
#pragma unroll
      for (int j2 = 0; j2 < 16; ++j2) gq += Gs[jj * 16 + j2] * u[j2];
      q += u[jj] * gq;
    }
    const float mean = s1 + o;
    const float e2 = q + 2.f * o * s1 + o * o;
    const float var = fmaxf(e2 - mean * mean, 0.f);
    mi4[e] = mean;
    rr[e] = rsqrtf(var + EPS);
  }
#pragma unroll
  for (int jj = 0; jj < 16; ++jj) {
    float4 u4 = *(const float4*)(U + (size_t)(b * 16 + jj) * 1024 + m0);
    ushort4 o = make_ushort4(f2bf(u4.x * rr[0]), f2bf(u4.y * rr[1]),
                             f2bf(u4.z * rr[2]), f2bf(u4.w * rr[3]));
    *(ushort4*)(U2b + (size_t)(b * 32 + jj) * 1024 + m0) = o;
  }
  float4 ob4 = *(const float4*)(ob + m0);
  ushort4 od = make_ushort4(
      f2bf((ob4.x - mi4[0]) * rr[0]), f2bf((ob4.y - mi4[1]) * rr[1]),
      f2bf((ob4.z - mi4[2]) * rr[2]), f2bf((ob4.w - mi4[3]) * rr[3]));
  *(ushort4*)(U2b + (size_t)(b * 32 + 16) * 1024 + m0) = od;
  ushort4 z = make_ushort4(0, 0, 0, 0);
#pragma unroll
  for (int jj = 17; jj < 32; ++jj)
    *(ushort4*)(U2b + (size_t)(b * 32 + jj) * 1024 + m0) = z;
}

// ---------------- W2op[b][32][1024] = U2b[b] @ wop^T (MFMA, M=32) ------------
__global__ __launch_bounds__(256)
void w2op_gemm(const u16* __restrict__ U2b, const u16* __restrict__ wop,
               float* __restrict__ W2op) {
  __shared__ u16 sA[32 * 64];
  __shared__ u16 sB[128 * 64];
  const int b = blockIdx.y;
  const int bn0 = blockIdx.x * 128;
  const int tid = threadIdx.x;
  const int w = tid >> 6, l = tid & 63;
  const int lr = l & 15, lk = l >> 4;
  const int swz = lr & 7;
  const int srow = tid >> 3;
  const int scol = ((tid & 7) ^ (srow & 7)) << 3;
  const u16* Ab = U2b + (size_t)b * 32768 + (size_t)srow * 1024 + scol;
  const u16* Bb = wop + (size_t)(bn0 + srow) * 1024 + scol;
  const size_t rstride32 = (size_t)32 * 1024;

  f32x4 acc[2][2] = {};
  for (int k0 = 0; k0 < 1024; k0 += 64) {
    glds16(Ab + k0, sA + w * 512);
#pragma unroll
    for (int p = 0; p < 4; ++p)
      glds16(Bb + p * rstride32 + k0, sB + p * 2048 + w * 512);
    __syncthreads();
#pragma unroll
    for (int ks = 0; ks < 2; ++ks) {
      const int off = (((ks << 2) + lk) ^ swz) << 3;
      bf16x8 af[2], bfr[2];
#pragma unroll
      for (int m = 0; m < 2; ++m)
        af[m] = *(const bf16x8*)(sA + (m * 16 + lr) * 64 + off);
#pragma unroll
      for (int n = 0; n < 2; ++n)
        bfr[n] = *(const bf16x8*)(sB + (w * 32 + n * 16 + lr) * 64 + off);
#pragma unroll
      for (int m = 0; m < 2; ++m)
#pragma unroll
        for (int n = 0; n < 2; ++n)
          acc[m][n] = __builtin_amdgcn_mfma_f32_16x16x32_bf16(af[m], bfr[n], acc[m][n], 0, 0, 0);
    }
    __syncthreads();
  }
#pragma unroll
  for (int m = 0; m < 2; ++m)
#pragma unroll
    for (int n = 0; n < 2; ++n)
#pragma unroll
      for (int i = 0; i < 4; ++i) {
        const int row = m * 16 + lk * 4 + i;
        const int col = bn0 + w * 32 + n * 16 + lr;
        W2op[((size_t)b * 32 + row) * 1024 + col] = acc[m][n][i];
      }
}

// ---------------- analytic BN stats of Z (partials over b-groups) ------------
__global__ __launch_bounds__(256)
void znstats_part(const float* __restrict__ W2op, const float* __restrict__ G,
                  const float* __restrict__ pbar, float* __restrict__ pmu,
                  float* __restrict__ pe2) {
  __shared__ float Gs[256], pb[16];
  const int m = blockIdx.x * 256 + threadIdx.x;
  const int bg = blockIdx.y;
  float amu = 0.f, ae2 = 0.f;
  for (int bi = 0; bi < 4; ++bi) {
    const int b = bg * 4 + bi;
    __syncthreads();
    Gs[threadIdx.x] = G[b * 256 + threadIdx.x];
    if (threadIdx.x < 16) pb[threadIdx.x] = pbar[b * 16 + threadIdx.x];
    __syncthreads();
    float wv[17];
#pragma unroll
    for (int jj = 0; jj < 17; ++jj) wv[jj] = W2op[((size_t)b * 32 + jj) * 1024 + m];
    float s1 = 0.f;
#pragma unroll
    for (int jj = 0; jj < 16; ++jj) s1 += pb[jj] * wv[jj];
    float q = 0.f;
#pragma unroll
    for (int jj = 0; jj < 16; ++jj) {
      float gq = 0.f;
#pragma unroll
      for (int j2 = 0; j2 < 16; ++j2) gq += Gs[jj * 16 + j2] * wv[j2];
      q += wv[jj] * gq;
    }
    const float cz = wv[16];
    amu += s1 + cz;
    ae2 += q + 2.f * cz * s1 + cz * cz;
  }
  pmu[bg * 1024 + m] = amu;
  pe2[bg * 1024 + m] = ae2;
}

__global__ __launch_bounds__(256)
void znfin(const float* __restrict__ pmu, const float* __restrict__ pe2,
           const float* __restrict__ g, const float* __restrict__ be,
           float* __restrict__ afin, float* __restrict__ cf0) {
  const int m = blockIdx.x * 256 + threadIdx.x;
  float mu = 0.f, e2 = 0.f;
#pragma unroll
  for (int i = 0; i < 8; ++i) { mu += pmu[i * 1024 + m]; e2 += pe2[i * 1024 + m]; }
  mu *= (1.f / 32.f); e2 *= (1.f / 32.f);
  const float var = fmaxf(e2 - mu * mu, 0.f);
  const float A = rsqrtf(var + EPS) * g[m];
  afin[m] = A;
  cf0[m] = be[m] - mu * A;
}

// ---------------- final: out[t,m] = sum_j P[t,j]*W2op[b][j,m]*A[m] + const ---
__global__ __launch_bounds__(256)
void zfinal(const float* __restrict__ P, const float* __restrict__ W2op,
            const float* __restrict__ afin, const float* __restrict__ cf0,
            float* __restrict__ out) {
  __shared__ float PL[512];            // 32 rows x 16 probs
  const int blk = blockIdx.x;          // 1024 blocks
  const int b = blk >> 5;
  const int r0 = blk * 32;             // global row base
  const int tid = threadIdx.x;
  const int col = tid * 4;

  f32x4 A4 = *(const f32x4*)(afin + col);
  f32x4 wreg[17];
#pragma unroll
  for (int jj = 0; jj < 17; ++jj) {
    f32x4 wv = *(const f32x4*)(W2op + ((size_t)b * 32 + jj) * 1024 + col);
    wreg[jj] = wv * A4;
  }
  const f32x4 basev = wreg[16] + *(const f32x4*)(cf0 + col);

  if (tid < 128)
    ((f32x4*)PL)[tid] = *(const f32x4*)(P + (size_t)r0 * 16 + tid * 4);
  __syncthreads();

  float* obase = out + (size_t)r0 * 1024 + col;
  for (int r = 0; r < 32; ++r) {
    const float* pr = PL + r * 16;
    f32x4 a = basev;
#pragma unroll
    for (int jj = 0; jj < 16; ++jj) a += pr[jj] * wreg[jj];
    *(f32x4*)(obase + (size_t)r * 1024) = a;
  }
}

// =============================================================================
extern "C" void kernel_launch(void* const* d_in, const int* in_sizes, int n_in,
                              void* d_out, int out_size, void* d_ws, size_t ws_size,
                              hipStream_t stream) {
  (void)in_sizes; (void)n_in; (void)out_size; (void)ws_size;

  const float* src      = (const float*)d_in[0];
  const float* lan      = (const float*)d_in[1];
  const float* qmask    = (const float*)d_in[3];
  const float* ip_w     = (const float*)d_in[4];
  const float* ip_g     = (const float*)d_in[6];
  const float* ip_beta  = (const float*)d_in[7];
  const float* lp_w     = (const float*)d_in[8];
  const float* lp_b     = (const float*)d_in[9];
  const float* mem_tok  = (const float*)d_in[10];
  const float* neg_tok  = (const float*)d_in[11];
  const float* vl_qw    = (const float*)d_in[12];
  const float* vl_qb    = (const float*)d_in[13];
  const float* vl_kw    = (const float*)d_in[14];
  const float* vl_kb    = (const float*)d_in[15];
  const float* mf_qw    = (const float*)d_in[20];
  const float* mf_qb    = (const float*)d_in[21];
  const float* mf_kw    = (const float*)d_in[22];
  const float* mf_kb    = (const float*)d_in[23];
  const float* mf_vw    = (const float*)d_in[24];
  const float* mf_vb    = (const float*)d_in[25];
  const float* mf_ow    = (const float*)d_in[26];
  const float* mf_ob    = (const float*)d_in[27];
  const float* ff_qw    = (const float*)d_in[28];
  const float* ff_qb    = (const float*)d_in[29];
  const float* ff_kw    = (const float*)d_in[30];
  const float* ff_kb    = (const float*)d_in[31];
  const float* ff_vw    = (const float*)d_in[32];
  const float* ff_vb    = (const float*)d_in[33];
  const float* ff_ow    = (const float*)d_in[34];
  const float* ff_ob    = (const float*)d_in[35];
  const float* op_w     = (const float*)d_in[36];
  const float* op_g     = (const float*)d_in[38];
  const float* op_beta  = (const float*)d_in[39];

  float* out_final = (float*)d_out;
  float* out_cur   = out_final + 33554432ull;
  float* out_vl    = out_cur + 65536ull;
  float* out_mem   = out_vl + 16777216ull;
  float* out_ff    = out_mem + 16384ull;

  // ---- workspace carve ----
  char* wp = (char*)d_ws;
  auto take = [&](size_t sz) { char* r = wp; wp += (sz + 255) & ~(size_t)255; return r; };
  u16*   W1   = (u16*)  take(67108864);    // Q2 (vl q'')
  u16*   W2   = (u16*)  take(67108864);    // Y1 (pre-BN ip output), live to ff_score
  u16*   LP   = (u16*)  take(4194304);     // lan_p bf16
  u16*   QV   = (u16*)  take(4194304);     // vl q bf16
  u16*   KM   = (u16*)  take(4194304);     // mf k bf16
  u16*   VM   = (u16*)  take(4194304);     // mf v bf16
  u16*   LANB = (u16*)  take(3145728);     // lan bf16
  u16*   wip  = (u16*)  take(2097152);
  u16*   wlp  = (u16*)  take(1572864);
  u16*   wvq  = (u16*)  take(2097152);
  u16*   wmk  = (u16*)  take(2097152);
  u16*   wmv  = (u16*)  take(2097152);
  u16*   wop  = (u16*)  take(2097152);     // op_w bf16 [m][c]
  u16*   wvkT = (u16*)  take(2097152);     // vl_kw^T bf16
  u16*   wfoT = (u16*)  take(2097152);     // ff_ow^T bf16
  u16*   w2ff = (u16*)  take(1048576);     // folded ff-q weights [32][16][1024]
  u16*   U2b  = (u16*)  take(2097152);     // [32][32][1024] bf16
  float* qmf   = (float*)take(4096);
  float* attvm = (float*)take(131072);
  float* memo  = (float*)take(131072);
  float* curw  = (float*)take(262144);
  float* kff   = (float*)take(262144);
  float* vff   = (float*)take(262144);
  float* ps    = (float*)take(1048576);    // [256][1024] partials
  float* pq    = (float*)take(1048576);
  float2* st1  = (float2*)take(8192);
  float* afv   = (float*)take(4096);
  float* cfv   = (float*)take(4096);
  float* wcv   = (float*)take(4096);
  float* cff   = (float*)take(2048);
  float* Pbuf  = (float*)take(2097152);    // [32768][16]
  float* Ub    = (float*)take(2097152);    // [32][16][1024]
  float* W2opb = (float*)take(4194304);    // [32][32][1024] f32
  float* Gb    = (float*)take(32768);      // [32][256]
  float* pbarb = (float*)take(2048);       // [32][16]
  float* Gpart = (float*)take(262144);     // [32][8][256]
  float* pbpart= (float*)take(16384);      // [32][8][16]
  float* pmu   = (float*)take(32768);      // [8][1024]
  float* pe2   = (float*)take(32768);      // [8][1024]
  float* afin  = (float*)take(4096);
  float* cf0   = (float*)take(4096);

  const dim3 blk(256);

  // conversions (weights + lan; src conversion fused into gemm_ip)
  {
    F2B8 j;
    const float* ins[7] = {lan, ip_w, lp_w, vl_qw, mf_kw, mf_vw, op_w};
    u16* outs[7] = {LANB, wip, wlp, wvq, wmk, wmv, wop};
    int n4s[7] = {393216, 262144, 196608, 262144, 262144, 262144, 262144};
    for (int i = 0; i < 7; ++i) { j.in[i] = ins[i]; j.out[i] = outs[i]; j.n4[i] = n4s[i]; }
    f2b_multi<<<dim3(1024, 7), blk, 0, stream>>>(j);
  }
  {
    WT2 g;
    g.W[0] = vl_kw; g.WT[0] = wvkT;
    g.W[1] = ff_ow; g.WT[1] = wfoT;
    wtrans2<<<dim3(16, 16, 2), blk, 0, stream>>>(g);
  }

  // stage 0: input proj (fused f32->bf16 + fused column stats) -> Y1 (W2)
  gemm_ip<<<dim3(8, 256), blk, 0, stream>>>(src, wip, W2, ps, pq, 32768, 1024, 1024);
  colstats_final<<<dim3(32), blk, 0, stream>>>(ps, pq, st1, ip_g, ip_beta, afv, cfv, 1.0f / 32768.0f);

  // lan proj, then {vl_q, mf_k, mf_v} in one z-batched launch
  gemm_bt<<<dim3(8, 16), blk, 0, stream>>>(LANB, wlp, lp_b, LP, 2048, 1024, 768);
  {
    G3 g;
    g.B[0] = wvq; g.bias[0] = vl_qb; g.C[0] = QV;
    g.B[1] = wmk; g.bias[1] = mf_kb; g.C[1] = KM;
    g.B[2] = wmv; g.bias[2] = mf_vb; g.C[2] = VM;
    gemm_bt_z<<<dim3(8, 16, 3), blk, 0, stream>>>(LP, g, 2048, 1024, 1024);
  }

  // stage 1 (vl, k-proj folded; fused score+softmax v4 w/ in-block cst)
  gemm_qpp<<<dim3(8, 16, 8), blk, 0, stream>>>(QV, wvkT, afv, W1);
  {
    VG2 g;
    g.A[0] = cfv;     g.W[0] = vl_kw; g.bias[0] = vl_kb; g.out[0] = wcv;
    g.A[1] = mem_tok; g.W[1] = mf_qw; g.bias[1] = mf_qb; g.out[1] = qmf;
    vec_gemm2<<<dim3(32, 1, 2), blk, 0, stream>>>(g);
  }
  vl_fused<<<dim3(256), dim3(512), 0, stream>>>(W1, W2, QV, wcv, qmask, out_vl);

  // stage 2 (memory fuse)
  mem_attn<<<dim3(32), blk, 0, stream>>>(qmf, KM, VM, qmask, out_mem, attvm);
  small_gemm<<<dim3(4, 32), blk, 0, stream>>>(attvm, mf_ow, mf_ob, memo, 1024, 1024);
  make_cur<<<dim3(128), blk, 0, stream>>>(neg_tok, memo, out_cur, curw);

  // stage 3 (feature fuse, fully rank-16 folded; score+softmax fused)
  {
    SG2 g;
    g.W[0] = ff_kw; g.bias[0] = ff_kb; g.out[0] = kff;
    g.W[1] = ff_vw; g.bias[1] = ff_vb; g.out[1] = vff;
    small_gemm2<<<dim3(4, 64, 2), blk, 0, stream>>>(curw, g, 1024, 1024);
  }
  ffw_fold<<<dim3(16, 32), blk, 0, stream>>>(kff, ff_qw, ff_qb, afv, cfv, w2ff, cff);
  ff_score<<<dim3(8, 32), blk, 0, stream>>>(W2, w2ff, cff, Pbuf, out_ff);
  pg_part<<<dim3(32, 8), blk, 0, stream>>>(Pbuf, Gpart, pbpart);
  ufold<<<dim3(16, 32), blk, 0, stream>>>(vff, wfoT, Ub);
  iprep<<<dim3(32), blk, 0, stream>>>(Ub, Gpart, pbpart, ff_ob, U2b, Gb, pbarb);
  w2op_gemm<<<dim3(8, 32), blk, 0, stream>>>(U2b, wop, W2opb);
  znstats_part<<<dim3(4, 8), blk, 0, stream>>>(W2opb, Gb, pbarb, pmu, pe2);
  znfin<<<dim3(4), blk, 0, stream>>>(pmu, pe2, op_g, op_beta, afin, cf0);
  zfinal<<<dim3(1024), blk, 0, stream>>>(Pbuf, W2opb, afin, cf0, out_final);
}

// Round 22
// 545.239 us; speedup vs baseline: 1.1059x; 1.1059x over previous
//
#include <hip/hip_runtime.h>
#include <stdint.h>

#define EPS 1e-5f
#define SCALE 0.08838834764831845f  /* 1/sqrt(128) */

typedef __bf16 bf16x8 __attribute__((ext_vector_type(8)));
typedef float f32x4 __attribute__((ext_vector_type(4)));
typedef unsigned short u16;
typedef unsigned int u32;
typedef u16 u16x8 __attribute__((ext_vector_type(8)));

__device__ __forceinline__ u16 f2bf(float f) {
  union { float f; u32 u; } x; x.f = f;
  u32 r = x.u + 0x7fffu + ((x.u >> 16) & 1u);
  return (u16)(r >> 16);
}
__device__ __forceinline__ float bf2f(u16 u) {
  union { u32 u; float f; } x; x.u = ((u32)u) << 16; return x.f;
}
__device__ __forceinline__ void glds16(const void* g, void* l) {
  __builtin_amdgcn_global_load_lds((__attribute__((address_space(1))) void*)g,
                                   (__attribute__((address_space(3))) void*)l,
                                   16, 0, 0);
}

// ---------------- f32 -> bf16 convert, up to 12 segments ---------------------
struct F2B12 {
  const float* in[12];
  u16* out[12];
  int n4[12];
};
__global__ __launch_bounds__(256) void f2b_multi(F2B12 j) {
  const int seg = blockIdx.y;
  const int n4 = j.n4[seg];
  const float* __restrict__ in = j.in[seg];
  u16* __restrict__ out = j.out[seg];
  for (int i = blockIdx.x * 256 + threadIdx.x; i < n4; i += gridDim.x * 256) {
    float4 v = ((const float4*)in)[i];
    ((ushort4*)out)[i] = make_ushort4(f2bf(v.x), f2bf(v.y), f2bf(v.z), f2bf(v.w));
  }
}

// ---------------- transpose weight x2: WT[m,n] = W[n,m], f32 -> bf16 ---------
struct WT2 { const float* W[2]; u16* WT[2]; };
__global__ __launch_bounds__(256)
void wtrans2(WT2 g) {
  __shared__ float tile[64][65];
  const float* __restrict__ W = g.W[blockIdx.z];
  u16* __restrict__ WT = g.WT[blockIdx.z];
  const int bx = blockIdx.x, by = blockIdx.y;   // 16 x 16 blocks of 64x64
  const int r = threadIdx.x >> 2, c0 = (threadIdx.x & 3) * 16;
  const float* src = W + (size_t)(by * 64 + r) * 1024 + bx * 64 + c0;
#pragma unroll
  for (int e = 0; e < 16; e += 4) {
    float4 v = *(const float4*)(src + e);
    tile[r][c0 + e] = v.x; tile[r][c0 + e + 1] = v.y;
    tile[r][c0 + e + 2] = v.z; tile[r][c0 + e + 3] = v.w;
  }
  __syncthreads();
  u16* dst = WT + (size_t)(bx * 64 + r) * 1024 + by * 64 + c0;
#pragma unroll
  for (int e = 0; e < 16; e += 4) {
    ushort4 o = make_ushort4(f2bf(tile[c0 + e][r]), f2bf(tile[c0 + e + 1][r]),
                             f2bf(tile[c0 + e + 2][r]), f2bf(tile[c0 + e + 3][r]));
    *(ushort4*)(dst + e) = o;
  }
}

// ---------------- ip GEMM (r14/r16 proven): 128x128, fused cvt+stats ---------
__global__ __launch_bounds__(256)
void gemm_ip(const float* __restrict__ Af, const u16* __restrict__ B,
             u16* __restrict__ Cb, float* __restrict__ ps,
             float* __restrict__ pq, int M, int N, int K) {
  __shared__ u16 sA[128 * 64];
  __shared__ u16 sB[128 * 64];
  const int nwg = (int)(gridDim.x * gridDim.y);
  const int chunk = nwg >> 3;
  int s = blockIdx.y * gridDim.x + blockIdx.x;
  int t = (s & 7) * chunk + (s >> 3);
  const int bn0 = (t & 7) * 128;
  const int bm0 = (t >> 3) * 128;
  const int tid = threadIdx.x;
  const int w = tid >> 6, l = tid & 63;
  const int wr = w >> 1, wc = w & 1;
  const int lr = l & 15, lk = l >> 4;
  const int swz = lr & 7;

  const int srow = tid >> 3;
  const int lslot = tid & 7;
  const int pslot = lslot ^ (srow & 7);
  const float* As = Af + (size_t)(bm0 + srow) * K + lslot * 8;   // linear
  const int scol = pslot << 3;   // B keeps pre-swizzled source
  const u16* Bb = B + (size_t)(bn0 + srow) * K + scol;
  const size_t rstride32 = (size_t)32 * K;

  f32x4 acc[4][4] = {};
  f32x4 pa0[4], pa1[4];
#pragma unroll
  for (int p = 0; p < 4; ++p) {
    const float* sp = As + (size_t)p * 32 * K;
    pa0[p] = *(const f32x4*)(sp);
    pa1[p] = *(const f32x4*)(sp + 4);
  }

  for (int k0 = 0; k0 < K; k0 += 64) {
#pragma unroll
    for (int p = 0; p < 4; ++p)
      glds16(Bb + p * rstride32 + k0, sB + p * 2048 + w * 512);
    // convert prefetched regs -> LDS (swizzled slot)
#pragma unroll
    for (int p = 0; p < 4; ++p) {
      u16x8 o;
      o[0] = f2bf(pa0[p][0]); o[1] = f2bf(pa0[p][1]);
      o[2] = f2bf(pa0[p][2]); o[3] = f2bf(pa0[p][3]);
      o[4] = f2bf(pa1[p][0]); o[5] = f2bf(pa1[p][1]);
      o[6] = f2bf(pa1[p][2]); o[7] = f2bf(pa1[p][3]);
      *(u16x8*)(sA + p * 2048 + srow * 64 + (pslot << 3)) = o;
    }
    __syncthreads();
    // T14 (post-barrier issue): loads overlap the MFMA phase
    if (k0 + 64 < K) {
#pragma unroll
      for (int p = 0; p < 4; ++p) {
        const float* sp = As + (size_t)p * 32 * K + k0 + 64;
        pa0[p] = *(const f32x4*)(sp);
        pa1[p] = *(const f32x4*)(sp + 4);
      }
    }
#pragma unroll
    for (int ks = 0; ks < 2; ++ks) {
      const int off = (((ks << 2) + lk) ^ swz) << 3;
      bf16x8 af[4], bfr[4];
#pragma unroll
      for (int m = 0; m < 4; ++m)
        af[m] = *(const bf16x8*)(sA + (wr * 64 + m * 16 + lr) * 64 + off);
#pragma unroll
      for (int n = 0; n < 4; ++n)
        bfr[n] = *(const bf16x8*)(sB + (wc * 64 + n * 16 + lr) * 64 + off);
#pragma unroll
      for (int m = 0; m < 4; ++m)
#pragma unroll
        for (int n = 0; n < 4; ++n)
          acc[m][n] = __builtin_amdgcn_mfma_f32_16x16x32_bf16(af[m], bfr[n], acc[m][n], 0, 0, 0);
    }
    __syncthreads();
  }

  // C-store
#pragma unroll
  for (int m = 0; m < 4; ++m) {
    const int grow0 = bm0 + wr * 64 + m * 16 + lk * 4;
#pragma unroll
    for (int n = 0; n < 4; ++n) {
      const int gcol = bn0 + wc * 64 + n * 16 + lr;
#pragma unroll
      for (int i = 0; i < 4; ++i)
        Cb[(size_t)(grow0 + i) * N + gcol] = f2bf(acc[m][n][i]);
    }
  }

  // fused column stats (f32 acc)
  float csum[4], csq[4];
#pragma unroll
  for (int n = 0; n < 4; ++n) {
    float s2 = 0.f, q2 = 0.f;
#pragma unroll
    for (int m = 0; m < 4; ++m)
#pragma unroll
      for (int i = 0; i < 4; ++i) {
        const float v = acc[m][n][i];
        s2 += v; q2 += v * v;
      }
    s2 += __shfl_xor(s2, 16, 64); q2 += __shfl_xor(q2, 16, 64);
    s2 += __shfl_xor(s2, 32, 64); q2 += __shfl_xor(q2, 32, 64);
    csum[n] = s2; csq[n] = q2;
  }
  float* cs = (float*)sA;
  float* cq = cs + 256;
  if (lk == 0) {
#pragma unroll
    for (int n = 0; n < 4; ++n) {
      cs[wr * 128 + wc * 64 + n * 16 + lr] = csum[n];
      cq[wr * 128 + wc * 64 + n * 16 + lr] = csq[n];
    }
  }
  __syncthreads();
  if (tid < 128) {
    const size_t o = (size_t)(bm0 >> 7) * 1024 + bn0 + tid;
    ps[o] = cs[tid] + cs[128 + tid];
    pq[o] = cq[tid] + cq[128 + tid];
  }
}

// ---------------- 128x128 bf16 GEMM (BK=64, T1+T2): C=A@B^T (+bias) ----------
__global__ __launch_bounds__(256)
void gemm_bt(const u16* __restrict__ A, const u16* __restrict__ B,
             const float* __restrict__ bias, u16* __restrict__ Cb,
             int M, int N, int K) {
  __shared__ u16 sA[128 * 64];
  __shared__ u16 sB[128 * 64];
  const int nwg = (int)(gridDim.x * gridDim.y);
  const int chunk = nwg >> 3;
  int s = blockIdx.y * gridDim.x + blockIdx.x;
  int t = (s & 7) * chunk + (s >> 3);
  const int bn0 = (t & 7) * 128;
  const int bm0 = (t >> 3) * 128;
  const int tid = threadIdx.x;
  const int w = tid >> 6, l = tid & 63;
  const int wr = w >> 1, wc = w & 1;
  const int lr = l & 15, lk = l >> 4;
  const int swz = lr & 7;

  const int srow = tid >> 3;
  const int scol = ((tid & 7) ^ (srow & 7)) << 3;
  const u16* Ab = A + (size_t)(bm0 + srow) * K + scol;
  const u16* Bb = B + (size_t)(bn0 + srow) * K + scol;
  const size_t rstride32 = (size_t)32 * K;

  f32x4 acc[4][4] = {};

  for (int k0 = 0; k0 < K; k0 += 64) {
#pragma unroll
    for (int p = 0; p < 4; ++p) {
      glds16(Ab + p * rstride32 + k0, sA + p * 2048 + w * 512);
      glds16(Bb + p * rstride32 + k0, sB + p * 2048 + w * 512);
    }
    __syncthreads();
#pragma unroll
    for (int ks = 0; ks < 2; ++ks) {
      const int off = (((ks << 2) + lk) ^ swz) << 3;
      bf16x8 af[4], bfr[4];
#pragma unroll
      for (int m = 0; m < 4; ++m)
        af[m] = *(const bf16x8*)(sA + (wr * 64 + m * 16 + lr) * 64 + off);
#pragma unroll
      for (int n = 0; n < 4; ++n)
        bfr[n] = *(const bf16x8*)(sB + (wc * 64 + n * 16 + lr) * 64 + off);
#pragma unroll
      for (int m = 0; m < 4; ++m)
#pragma unroll
        for (int n = 0; n < 4; ++n)
          acc[m][n] = __builtin_amdgcn_mfma_f32_16x16x32_bf16(af[m], bfr[n], acc[m][n], 0, 0, 0);
    }
    __syncthreads();
  }

#pragma unroll
  for (int m = 0; m < 4; ++m) {
    const int grow0 = bm0 + wr * 64 + m * 16 + lk * 4;
#pragma unroll
    for (int n = 0; n < 4; ++n) {
      const int gcol = bn0 + wc * 64 + n * 16 + lr;
      const float bv = bias ? bias[gcol] : 0.0f;
#pragma unroll
      for (int i = 0; i < 4; ++i) {
        const float v = acc[m][n][i] + bv;
        Cb[(size_t)(grow0 + i) * N + gcol] = f2bf(v);
      }
    }
  }
}

// ---------------- gemm_bt with grid.z selecting 1 of 3 weight sets -----------
struct G3 { const u16* B[3]; const float* bias[3]; u16* C[3]; };
__global__ __launch_bounds__(256)
void gemm_bt_z(const u16* __restrict__ A, G3 g, int M, int N, int K) {
  __shared__ u16 sA[128 * 64];
  __shared__ u16 sB[128 * 64];
  const int z = blockIdx.z;
  const u16* __restrict__ B = g.B[z];
  const float* __restrict__ bias = g.bias[z];
  u16* __restrict__ Cb = g.C[z];
  const int nwg = (int)(gridDim.x * gridDim.y);
  const int chunk = nwg >> 3;
  int s = blockIdx.y * gridDim.x + blockIdx.x;
  int t = (s & 7) * chunk + (s >> 3);
  const int bn0 = (t & 7) * 128;
  const int bm0 = (t >> 3) * 128;
  const int tid = threadIdx.x;
  const int w = tid >> 6, l = tid & 63;
  const int wr = w >> 1, wc = w & 1;
  const int lr = l & 15, lk = l >> 4;
  const int swz = lr & 7;

  const int srow = tid >> 3;
  const int scol = ((tid & 7) ^ (srow & 7)) << 3;
  const u16* Ab = A + (size_t)(bm0 + srow) * K + scol;
  const u16* Bb = B + (size_t)(bn0 + srow) * K + scol;
  const size_t rstride32 = (size_t)32 * K;

  f32x4 acc[4][4] = {};

  for (int k0 = 0; k0 < K; k0 += 64) {
#pragma unroll
    for (int p = 0; p < 4; ++p) {
      glds16(Ab + p * rstride32 + k0, sA + p * 2048 + w * 512);
      glds16(Bb + p * rstride32 + k0, sB + p * 2048 + w * 512);
    }
    __syncthreads();
#pragma unroll
    for (int ks = 0; ks < 2; ++ks) {
      const int off = (((ks << 2) + lk) ^ swz) << 3;
      bf16x8 af[4], bfr[4];
#pragma unroll
      for (int m = 0; m < 4; ++m)
        af[m] = *(const bf16x8*)(sA + (wr * 64 + m * 16 + lr) * 64 + off);
#pragma unroll
      for (int n = 0; n < 4; ++n)
        bfr[n] = *(const bf16x8*)(sB + (wc * 64 + n * 16 + lr) * 64 + off);
#pragma unroll
      for (int m = 0; m < 4; ++m)
#pragma unroll
        for (int n = 0; n < 4; ++n)
          acc[m][n] = __builtin_amdgcn_mfma_f32_16x16x32_bf16(af[m], bfr[n], acc[m][n], 0, 0, 0);
    }
    __syncthreads();
  }

#pragma unroll
  for (int m = 0; m < 4; ++m) {
    const int grow0 = bm0 + wr * 64 + m * 16 + lk * 4;
#pragma unroll
    for (int n = 0; n < 4; ++n) {
      const int gcol = bn0 + wc * 64 + n * 16 + lr;
      const float bv = bias[gcol];
#pragma unroll
      for (int i = 0; i < 4; ++i)
        Cb[(size_t)(grow0 + i) * N + gcol] = f2bf(acc[m][n][i] + bv);
    }
  }
}

// ---------------- q'' GEMM: Q2[b*512+h*64+i, m] = (QV[:,hs]@WT[:,hs]^T)*a[m] -
__global__ __launch_bounds__(256)
void gemm_qpp(const u16* __restrict__ QV, const u16* __restrict__ WT,
              const float* __restrict__ afv, u16* __restrict__ Q2) {
  __shared__ u16 sA[128 * 64];
  __shared__ u16 sB[128 * 64];
  const int h = blockIdx.z;
  int s = blockIdx.y * 8 + blockIdx.x;
  int t = (s & 7) * 16 + (s >> 3);
  const int bn0 = (t & 7) * 128;
  const int bm0 = (t >> 3) * 128;
  const int tid = threadIdx.x;
  const int w = tid >> 6, l = tid & 63;
  const int wr = w >> 1, wc = w & 1;
  const int lr = l & 15, lk = l >> 4;
  const int swz = lr & 7;

  const int srow = tid >> 3;
  const int scol = ((tid & 7) ^ (srow & 7)) << 3;
  const u16* Ab = QV + (size_t)(bm0 + srow) * 1024 + h * 128 + scol;
  const u16* Bb = WT + (size_t)(bn0 + srow) * 1024 + h * 128 + scol;
  const size_t rstride32 = (size_t)32 * 1024;

  f32x4 acc[4][4] = {};

  for (int k0 = 0; k0 < 128; k0 += 64) {
#pragma unroll
    for (int p = 0; p < 4; ++p) {
      glds16(Ab + p * rstride32 + k0, sA + p * 2048 + w * 512);
      glds16(Bb + p * rstride32 + k0, sB + p * 2048 + w * 512);
    }
    __syncthreads();
#pragma unroll
    for (int ks = 0; ks < 2; ++ks) {
      const int off = (((ks << 2) + lk) ^ swz) << 3;
      bf16x8 af[4], bfr[4];
#pragma unroll
      for (int m = 0; m < 4; ++m)
        af[m] = *(const bf16x8*)(sA + (wr * 64 + m * 16 + lr) * 64 + off);
#pragma unroll
      for (int n = 0; n < 4; ++n)
        bfr[n] = *(const bf16x8*)(sB + (wc * 64 + n * 16 + lr) * 64 + off);
#pragma unroll
      for (int m = 0; m < 4; ++m)
#pragma unroll
        for (int n = 0; n < 4; ++n)
          acc[m][n] = __builtin_amdgcn_mfma_f32_16x16x32_bf16(af[m], bfr[n], acc[m][n], 0, 0, 0);
    }
    __syncthreads();
  }

#pragma unroll
  for (int m = 0; m < 4; ++m) {
    const int grow0 = bm0 + wr * 64 + m * 16 + lk * 4;
#pragma unroll
    for (int n = 0; n < 4; ++n) {
      const int gcol = bn0 + wc * 64 + n * 16 + lr;
      const float a = afv[gcol];
#pragma unroll
      for (int i = 0; i < 4; ++i) {
        const int gr = grow0 + i;
        const int q2row = ((gr >> 6) << 9) + h * 64 + (gr & 63);
        Q2[(size_t)q2row * 1024 + gcol] = f2bf(acc[m][n][i] * a);
      }
    }
  }
}

// ---------------- fused vl score + softmax v4: + in-block cst ----------------
__global__ __launch_bounds__(512)
void vl_fused(const u16* __restrict__ Q2, const u16* __restrict__ Y1,
              const u16* __restrict__ QV, const float* __restrict__ wcv,
              const float* __restrict__ qmask, float* __restrict__ out) {
  __shared__ u16 sA[2 * 8192];       // 2 x (64 rows x 128 cols) bf16
  __shared__ float redmx[64][8];
  __shared__ float redsm[64][8];
  __shared__ float cst_s[64];
  const int blk = blockIdx.x;       // 256
  const int xcd = blk & 7;
  const int idx = blk >> 3;         // 0..31
  const int b = xcd + 8 * (idx >> 3);
  const int r0 = (idx & 7) * 64;    // row base within b's 512
  const int h = r0 >> 6;            // single head per block
  const int tid = threadIdx.x;
  const int w = tid >> 6, l = tid & 63;
  const int lr = l & 15, lk = l >> 4;

  const int arow0 = tid >> 4;             // 0..31
  const int aslot = tid & 15;
  const u16* Asrc0 = Q2 + (size_t)(b * 512 + r0 + arow0) * 1024 +
                     ((aslot ^ (arow0 & 7)) << 3);
  const u16* Asrc1 = Q2 + (size_t)(b * 512 + 32 + r0 + arow0) * 1024 +
                     ((aslot ^ ((32 + arow0) & 7)) << 3);
  const u16* Brow = Y1 + (size_t)b * 1048576 + (size_t)(w * 128 + lr) * 1024 + lk * 8;

  f32x4 acc[4][8] = {};

  // prologue: stage chunk 0 into buf 0
  glds16(Asrc0, sA + w * 512);
  glds16(Asrc1, sA + 4096 + w * 512);

  // in-block cst: cst_s[j] = QV[b*64+j][h*128:+128] . wcv[h*128:+128]
  {
    const int j = tid >> 3, t8 = tid & 7;
    const u16* qp = QV + (size_t)(b * 64 + j) * 1024 + h * 128 + t8 * 16;
    const float* wp_ = wcv + h * 128 + t8 * 16;
    u16x8 v0 = *(const u16x8*)(qp);
    u16x8 v1 = *(const u16x8*)(qp + 8);
    float sacc = 0.f;
#pragma unroll
    for (int e = 0; e < 8; ++e) sacc += bf2f(v0[e]) * wp_[e];
#pragma unroll
    for (int e = 0; e < 8; ++e) sacc += bf2f(v1[e]) * wp_[8 + e];
    sacc += __shfl_xor(sacc, 1, 64);
    sacc += __shfl_xor(sacc, 2, 64);
    sacc += __shfl_xor(sacc, 4, 64);
    if (t8 == 0) cst_s[j] = sacc;
  }

  for (int c = 0; c < 8; ++c) {
    __syncthreads();                       // buf[c] ready; prev reads done
    const u16* sAc = sA + (c & 1) * 8192;
    if (c < 7) {                           // stage next chunk into other buf
      const int k1 = (c + 1) * 128;
      u16* d = sA + ((c + 1) & 1) * 8192;
      glds16(Asrc0 + k1, d + w * 512);
      glds16(Asrc1 + k1, d + 4096 + w * 512);
    }
    const int k0 = c * 128;
#pragma unroll
    for (int ks = 0; ks < 4; ++ks) {
      bf16x8 af[4];
#pragma unroll
      for (int m = 0; m < 4; ++m) {
        const int row = m * 16 + lr;
        af[m] = *(const bf16x8*)(sAc + row * 128 + ((((ks << 2) + lk) ^ (lr & 7)) << 3));
      }
      const int kc = k0 + (ks << 5);
#pragma unroll
      for (int n = 0; n < 8; ++n) {
        bf16x8 bf_ = *(const bf16x8*)(Brow + (size_t)n * 16384 + kc);
#pragma unroll
        for (int m = 0; m < 4; ++m)
          acc[m][n] = __builtin_amdgcn_mfma_f32_16x16x32_bf16(af[m], bf_, acc[m][n], 0, 0, 0);
      }
    }
  }

  float cst_r[4][4], scl[4][4];
#pragma unroll
  for (int m = 0; m < 4; ++m)
#pragma unroll
    for (int i = 0; i < 4; ++i) {
      const int rl = m * 16 + lk * 4 + i;   // = rem - r0 = rem & 63
      cst_r[m][i] = cst_s[rl];
      scl[m][i] = qmask[b * 64 + rl] * SCALE;
    }
#pragma unroll
  for (int m = 0; m < 4; ++m)
#pragma unroll
    for (int n = 0; n < 8; ++n)
#pragma unroll
      for (int i = 0; i < 4; ++i)
        acc[m][n][i] = (acc[m][n][i] + cst_r[m][i]) * scl[m][i];

  float mx[4][4];
#pragma unroll
  for (int m = 0; m < 4; ++m)
#pragma unroll
    for (int i = 0; i < 4; ++i) {
      float v = -3.4e38f;
#pragma unroll
      for (int n = 0; n < 8; ++n) v = fmaxf(v, acc[m][n][i]);
      for (int o = 1; o < 16; o <<= 1) v = fmaxf(v, __shfl_xor(v, o, 64));
      mx[m][i] = v;
    }
  if (lr == 0) {
#pragma unroll
    for (int m = 0; m < 4; ++m)
#pragma unroll
      for (int i = 0; i < 4; ++i)
        redmx[m * 16 + lk * 4 + i][w] = mx[m][i];
  }
  __syncthreads();
#pragma unroll
  for (int m = 0; m < 4; ++m)
#pragma unroll
    for (int i = 0; i < 4; ++i) {
      const int rl = m * 16 + lk * 4 + i;
      float v = redmx[rl][0];
#pragma unroll
      for (int ww = 1; ww < 8; ++ww) v = fmaxf(v, redmx[rl][ww]);
      mx[m][i] = v;
    }

  float sm[4][4];
#pragma unroll
  for (int m = 0; m < 4; ++m)
#pragma unroll
    for (int i = 0; i < 4; ++i) {
      float s = 0.f;
#pragma unroll
      for (int n = 0; n < 8; ++n) {
        float e = expf(acc[m][n][i] - mx[m][i]);
        acc[m][n][i] = e;
        s += e;
      }
      for (int o = 1; o < 16; o <<= 1) s += __shfl_xor(s, o, 64);
      sm[m][i] = s;
    }
  if (lr == 0) {
#pragma unroll
    for (int m = 0; m < 4; ++m)
#pragma unroll
      for (int i = 0; i < 4; ++i)
        redsm[m * 16 + lk * 4 + i][w] = sm[m][i];
  }
  __syncthreads();
#pragma unroll
  for (int m = 0; m < 4; ++m)
#pragma unroll
    for (int i = 0; i < 4; ++i) {
      const int rl = m * 16 + lk * 4 + i;
      float s = 0.f;
#pragma unroll
      for (int ww = 0; ww < 8; ++ww) s += redsm[rl][ww];
      sm[m][i] = 1.0f / s;
    }

#pragma unroll
  for (int m = 0; m < 4; ++m)
#pragma unroll
    for (int i = 0; i < 4; ++i) {
      const size_t grow = (size_t)(b * 512 + r0 + m * 16 + lk * 4 + i);
#pragma unroll
      for (int n = 0; n < 8; ++n)
        out[grow * 1024 + w * 128 + n * 16 + lr] = acc[m][n][i] * sm[m][i];
    }
}

// ---------------- reduce 256 chunks -> stats + BN-fold vectors a, c ----------
__global__ __launch_bounds__(256)
void colstats_final(const float* __restrict__ ps, const float* __restrict__ pq,
                    float2* __restrict__ st, const float* __restrict__ g,
                    const float* __restrict__ be, float* __restrict__ afv,
                    float* __restrict__ cfv, float inv_n) {
  __shared__ float rs_[8][32], rq_[8][32];
  const int cg = threadIdx.x >> 5, cl = threadIdx.x & 31;
  const int col = blockIdx.x * 32 + cl;
  float s = 0.f, q = 0.f;
  for (int i = 0; i < 32; ++i) {
    const size_t idx = (size_t)(cg * 32 + i) * 1024 + col;
    s += ps[idx]; q += pq[idx];
  }
  rs_[cg][cl] = s; rq_[cg][cl] = q;
  __syncthreads();
  if (cg == 0) {
    for (int i = 1; i < 8; ++i) { s += rs_[i][cl]; q += rq_[i][cl]; }
    const float m = s * inv_n;
    const float v = q * inv_n - m * m;
    const float rs = rsqrtf(v + EPS);
    st[col] = make_float2(m, rs);
    if (afv) {
      const float a = rs * g[col];
      afv[col] = a;
      cfv[col] = be[col] - m * a;
    }
  }
}

// ---------------- small GEMM, bf16 W: out[m,n] = A[m,:]·Wb[n,:] + bias[n] ----
__global__ __launch_bounds__(256)
void small_gemm_bf(const float* __restrict__ A, const u16* __restrict__ Wb,
                   const float* __restrict__ bias, float* __restrict__ out,
                   int N, int K) {
  __shared__ float sA[1024];
  const int m = blockIdx.y;
  const int n = blockIdx.x * 256 + threadIdx.x;
  for (int i = threadIdx.x; i < K; i += 256) sA[i] = A[(size_t)m * K + i];
  __syncthreads();
  const u16* wr = Wb + (size_t)n * K;
  float acc = bias ? bias[n] : 0.0f;
  for (int k = 0; k < K; k += 8) {
    u16x8 wv = *(const u16x8*)(wr + k);
#pragma unroll
    for (int e = 0; e < 8; ++e) acc += sA[k + e] * bf2f(wv[e]);
  }
  out[(size_t)m * N + n] = acc;
}

// ---------------- small bf16-W GEMM, grid.z selects 1 of 2 sets --------------
struct SGB2 { const u16* W[2]; const float* bias[2]; float* out[2]; };
__global__ __launch_bounds__(256)
void small_gemm2_bf(const float* __restrict__ A, SGB2 g, int N, int K) {
  __shared__ float sA[1024];
  const int z = blockIdx.z;
  const int m = blockIdx.y;
  const int n = blockIdx.x * 256 + threadIdx.x;
  for (int i = threadIdx.x; i < K; i += 256) sA[i] = A[(size_t)m * K + i];
  __syncthreads();
  const u16* wr = g.W[z] + (size_t)n * K;
  float acc = g.bias[z][n];
  for (int k = 0; k < K; k += 8) {
    u16x8 wv = *(const u16x8*)(wr + k);
#pragma unroll
    for (int e = 0; e < 8; ++e) acc += sA[k + e] * bf2f(wv[e]);
  }
  g.out[z][(size_t)m * N + n] = acc;
}

// ---------------- 1-row vec GEMM x2: out[n] = A·W[n,:] + b[n], 8 thr/output --
struct VG2 { const float* A[2]; const float* W[2]; const float* bias[2]; float* out[2]; };
__global__ __launch_bounds__(256)
void vec_gemm2(VG2 g) {
  __shared__ float sAv[1024];
  const int z = blockIdx.z;
  const float* __restrict__ A = g.A[z];
  const float* __restrict__ W = g.W[z];
  const int tid = threadIdx.x;
  ((float4*)sAv)[tid] = ((const float4*)A)[tid];
  __syncthreads();
  const int og = tid >> 3, t8 = tid & 7;
  const int n = blockIdx.x * 32 + og;
  const float* wr = W + (size_t)n * 1024;
  float s = 0.f;
#pragma unroll
  for (int j = 0; j < 32; ++j) {
    const int k = j * 32 + t8 * 4;
    float4 wv = *(const float4*)(wr + k);
    float4 av = *(const float4*)(sAv + k);
    s += av.x * wv.x + av.y * wv.y + av.z * wv.z + av.w * wv.w;
  }
  s += __shfl_xor(s, 1, 64);
  s += __shfl_xor(s, 2, 64);
  s += __shfl_xor(s, 4, 64);
  if (t8 == 0) g.out[z][n] = s + g.bias[z][n];
}

// ---------------- memory-fuse attention v2: per-(b,h) blocks -----------------
// 256 blocks (8x parallelism vs v1). Scores: 4 lanes/row + shuffle-reduce;
// softmax on one wave; PV with fully-coalesced 128-col reads.
__global__ __launch_bounds__(256)
void mem_attn(const float* __restrict__ qmf, const u16* __restrict__ KM,
              const u16* __restrict__ VM, const float* __restrict__ mask,
              float* __restrict__ att_out, float* __restrict__ attv_out) {
  __shared__ float qs[128];
  __shared__ float sM[64];
  __shared__ float sP[64];
  __shared__ float red[128];
  const int bh = blockIdx.x;       // 32 b x 8 h
  const int b = bh >> 3, h = bh & 7;
  const int tid = threadIdx.x;
  if (tid < 128) qs[tid] = qmf[h * 128 + tid];
  if (tid < 64) sM[tid] = mask[b * 64 + tid];
  __syncthreads();
  // scores: j = tid>>2, quarter q4 = tid&3 covers 32 of the 128 dims
  {
    const int j = tid >> 2, q4 = tid & 3;
    const u16* kr = KM + (size_t)(b * 64 + j) * 1024 + h * 128 + q4 * 32;
    float acc = 0.f;
#pragma unroll
    for (int d = 0; d < 32; d += 8) {
      u16x8 v = *(const u16x8*)(kr + d);
#pragma unroll
      for (int e = 0; e < 8; ++e) acc += qs[q4 * 32 + d + e] * bf2f(v[e]);
    }
    acc += __shfl_xor(acc, 1, 64);
    acc += __shfl_xor(acc, 2, 64);
    if (q4 == 0) sP[j] = acc * sM[j] * SCALE;
  }
  __syncthreads();
  // softmax over 64 keys on wave 0
  if (tid < 64) {
    float s = sP[tid];
    float mx = s;
    for (int o = 1; o < 64; o <<= 1) mx = fmaxf(mx, __shfl_xor(mx, o, 64));
    float e = expf(s - mx);
    float sum = e;
    for (int o = 1; o < 64; o <<= 1) sum += __shfl_xor(sum, o, 64);
    float p = e / sum;
    sP[tid] = p;
    att_out[(size_t)(b * 8 + h) * 64 + tid] = p;
  }
  __syncthreads();
  // PV: col = tid&127 (coalesced), jg = tid>>7 covers half the keys
  {
    const int c = tid & 127, jg = tid >> 7;
    float acc = 0.f;
    for (int j = jg * 32; j < jg * 32 + 32; ++j)
      acc += sP[j] * sM[j] * bf2f(VM[(size_t)(b * 64 + j) * 1024 + h * 128 + c]);
    if (jg) red[c] = acc;
    __syncthreads();
    if (!jg) attv_out[(size_t)b * 1024 + h * 128 + c] = acc + red[c];
  }
}

// ---------------- cur = inorm(concat(neg_tok, mem_out)) ----------------------
__global__ __launch_bounds__(256)
void make_cur(const float* __restrict__ neg, const float* __restrict__ memo,
              float* __restrict__ cur_out, float* __restrict__ curw) {
  const int i = blockIdx.x * 256 + threadIdx.x;   // 32768
  const int b = i >> 10, c = i & 1023;
  const float a = neg[c], x = memo[i];
  const float mean = 0.5f * (a + x);
  const float d = a - mean;
  const float rs = rsqrtf(d * d + EPS);
  const float o0 = d * rs, o1 = -d * rs;
  cur_out[(size_t)(b * 2) * 1024 + c] = o0;
  cur_out[(size_t)(b * 2 + 1) * 1024 + c] = o1;
  curw[(size_t)(b * 2) * 1024 + c] = o0;
  curw[(size_t)(b * 2 + 1) * 1024 + c] = o1;
}

// ---------------- ff fold (bf16 wfq): w''[b,j,h,:] and const_ff[b,j,h] -------
__global__ __launch_bounds__(256)
void ffw_fold(const float* __restrict__ kff, const u16* __restrict__ wfqb,
              const float* __restrict__ qb, const float* __restrict__ afv,
              const float* __restrict__ cfv, u16* __restrict__ w2ff,
              float* __restrict__ cff) {
  __shared__ float redl[4];
  const int b = blockIdx.y, jh = blockIdx.x;
  const int j = jh >> 3, h = jh & 7;
  const int tid = threadIdx.x;
  const int m0 = tid * 4;
  const float* kp = kff + (size_t)b * 2048 + j * 1024 + h * 128;
  float a0 = 0, a1 = 0, a2 = 0, a3 = 0;
  for (int n = 0; n < 128; ++n) {
    const float kv = kp[n];
    ushort4 wv = *(const ushort4*)(wfqb + (size_t)(h * 128 + n) * 1024 + m0);
    a0 += kv * bf2f(wv.x); a1 += kv * bf2f(wv.y);
    a2 += kv * bf2f(wv.z); a3 += kv * bf2f(wv.w);
  }
  float cpart = a0 * cfv[m0] + a1 * cfv[m0 + 1] + a2 * cfv[m0 + 2] + a3 * cfv[m0 + 3];
  if (tid < 128) cpart += qb[h * 128 + tid] * kp[tid];
  ushort4 o = make_ushort4(f2bf(a0 * afv[m0]), f2bf(a1 * afv[m0 + 1]),
                           f2bf(a2 * afv[m0 + 2]), f2bf(a3 * afv[m0 + 3]));
  *(ushort4*)(w2ff + (size_t)(b * 16 + jh) * 1024 + m0) = o;
  for (int o2 = 32; o2 > 0; o2 >>= 1) cpart += __shfl_xor(cpart, o2, 64);
  if ((tid & 63) == 0) redl[tid >> 6] = cpart;
  __syncthreads();
  if (tid == 0) cff[b * 16 + jh] = redl[0] + redl[1] + redl[2] + redl[3];
}

// ---------------- ff score v2: reg-direct A (no reuse => no staging) ---------
__global__ __launch_bounds__(256)
void ff_score(const u16* __restrict__ Y1, const u16* __restrict__ w2ff,
              const float* __restrict__ cff, float* __restrict__ P,
              float* __restrict__ att_out) {
  __shared__ u16 sB[16 * 1024];
  const int chunk = blockIdx.x, b = blockIdx.y;
  const int tid = threadIdx.x;
  const int w = tid >> 6, l = tid & 63;
  const int lr = l & 15, lk = l >> 4;
  const int swz = lr & 7;

  {
    const int n = tid >> 4;
    const int sb = (tid & 15) * 8;
#pragma unroll
    for (int v = 0; v < 8; ++v) {
      const int sidx = sb + v;
      u16x8 val = *(const u16x8*)(w2ff + (size_t)(b * 16 + n) * 1024 + sidx * 8);
      *(u16x8*)(sB + n * 1024 + ((sidx ^ (n & 7)) << 3)) = val;
    }
  }
  __syncthreads();

  const u16* Ar = Y1 + ((size_t)(b * 1024 + chunk * 128) + w * 32 + lr) * 1024 + lk * 8;
  f32x4 acc[2] = {};
#pragma unroll 4
  for (int k0 = 0; k0 < 1024; k0 += 32) {
    bf16x8 a0 = *(const bf16x8*)(Ar + k0);
    bf16x8 a1 = *(const bf16x8*)(Ar + 16 * 1024 + k0);
    const int bs = (k0 >> 3) + lk;
    bf16x8 bf_ = *(const bf16x8*)(sB + lr * 1024 + ((bs ^ swz) << 3));
    acc[0] = __builtin_amdgcn_mfma_f32_16x16x32_bf16(a0, bf_, acc[0], 0, 0, 0);
    acc[1] = __builtin_amdgcn_mfma_f32_16x16x32_bf16(a1, bf_, acc[1], 0, 0, 0);
  }

  const float cadd = cff[b * 16 + lr];
  const int h = lr & 7, jj = lr >> 3;
#pragma unroll
  for (int m = 0; m < 2; ++m)
#pragma unroll
    for (int i = 0; i < 4; ++i) {
      const float sval = (acc[m][i] + cadd) * SCALE;
      const float other = __shfl_xor(sval, 8, 64);
      const float mx = fmaxf(sval, other);
      const float e0 = expf(sval - mx), e1 = expf(other - mx);
      const float p = e0 / (e0 + e1);
      const int trow = chunk * 128 + w * 32 + m * 16 + lk * 4 + i;
      P[((size_t)b * 1024 + trow) * 16 + lr] = p;
      att_out[((size_t)(b * 8 + h) * 1024 + trow) * 2 + jj] = p;
    }
}

// ---------------- pbar/G partials: grid (32 b, 8 chunks) ---------------------
__global__ __launch_bounds__(256)
void pg_part(const float* __restrict__ P, float* __restrict__ Gp,
             float* __restrict__ pbarp) {
  __shared__ float Pl[128][16];
  const int b = blockIdx.x, c = blockIdx.y;
  const int tid = threadIdx.x;
  const int j = tid >> 4, j2 = tid & 15;
  for (int i = tid; i < 2048; i += 256)
    Pl[i >> 4][i & 15] = P[((size_t)b * 1024 + c * 128 + (i >> 4)) * 16 + (i & 15)];
  __syncthreads();
  float acc = 0.f, accp = 0.f;
  for (int t = 0; t < 128; ++t) {
    acc += Pl[t][j] * Pl[t][j2];
    if (j == 0) accp += Pl[t][j2];
  }
  Gp[(size_t)(b * 8 + c) * 256 + tid] = acc;
  if (j == 0) pbarp[(b * 8 + c) * 16 + j2] = accp;
}

// ---------------- U[b][jh][m] = sum_d vff[b,j,h*128+d] * wfo[m,h*128+d] ------
__global__ __launch_bounds__(256)
void ufold(const float* __restrict__ vff, const u16* __restrict__ wfoT,
           float* __restrict__ U) {
  const int b = blockIdx.y, jh = blockIdx.x;
  const int j = jh >> 3, h = jh & 7;
  const int m0 = threadIdx.x * 4;
  const float* vp = vff + (size_t)b * 2048 + j * 1024 + h * 128;
  float a0 = 0, a1 = 0, a2 = 0, a3 = 0;
  for (int d = 0; d < 128; ++d) {
    const float kv = vp[d];
    ushort4 wv = *(const ushort4*)(wfoT + (size_t)(h * 128 + d) * 1024 + m0);
    a0 += kv * bf2f(wv.x); a1 += kv * bf2f(wv.y);
    a2 += kv * bf2f(wv.z); a3 += kv * bf2f(wv.w);
  }
  *(float4*)(U + (size_t)(b * 16 + jh) * 1024 + m0) = make_float4(a0, a1, a2, a3);
}

// ---------------- merged: pg-final + analytic inorm stats + U2b prep ---------
__global__ __launch_bounds__(256)
void iprep(const float* __restrict__ U, const float* __restrict__ Gp,
           const float* __restrict__ pbp, const float* __restrict__ ob,
           u16* __restrict__ U2b, float* __restrict__ G,
           float* __restrict__ pbar) {
  __shared__ float Gs[256], pb[16];
  const int b = blockIdx.x;
  const int tid = threadIdx.x;
  {
    float s = 0.f;
#pragma unroll
    for (int c = 0; c < 8; ++c) s += Gp[(size_t)(b * 8 + c) * 256 + tid];
    s *= (1.f / 1024.f);
    Gs[tid] = s;
    G[b * 256 + tid] = s;
    if (tid < 16) {
      float p = 0.f;
#pragma unroll
      for (int c = 0; c < 8; ++c) p += pbp[(b * 8 + c) * 16 + tid];
      p *= (1.f / 1024.f);
      pb[tid] = p;
      pbar[b * 16 + tid] = p;
    }
  }
  __syncthreads();
  const int m0 = tid * 4;
  float rr[4], mi4[4];
#pragma unroll
  for (int e = 0; e < 4; ++e) {
    const int m = m0 + e;
    float u[16];
#pragma unroll
    for (int jj = 0; jj < 16; ++jj) u[jj] = U[(size_t)(b * 16 + jj) * 1024 + m];
    const float o = ob[m];
    float s1 = 0.f;
#pragma unroll
    for (int jj = 0; jj < 16; ++jj) s1 += pb[jj] * u[jj];
    float q = 0.f;
#pragma unroll
    for (int jj = 0; jj < 16; ++jj) {
      float gq = 0.f;
#pragma unroll
      for (int j2 = 0; j2 < 16; ++j2) gq += Gs[jj * 16 + j2] * u[j2];
      q += u[jj] * gq;
    }
    const float mean = s1 + o;
    const float e2 = q + 2.f * o * s1 + o * o;
    const float var = fmaxf(e2 - mean * mean, 0.f);
    mi4[e] = mean;
    rr[e] = rsqrtf(var + EPS);
  }
#pragma unroll
  for (int jj = 0; jj < 16; ++jj) {
    float4 u4 = *(const float4*)(U + (size_t)(b * 16 + jj) * 1024 + m0);
    ushort4 o = make_ushort4(f2bf(u4.x * rr[0]), f2bf(u4.y * rr[1]),
                             f2bf(u4.z * rr[2]), f2bf(u4.w * rr[3]));
    *(ushort4*)(U2b + (size_t)(b * 32 + jj) * 1024 + m0) = o;
  }
  float4 ob4 = *(const float4*)(ob + m0);
  ushort4 od = make_ushort4(
      f2bf((ob4.x - mi4[0]) * rr[0]), f2bf((ob4.y - mi4[1]) * rr[1]),
      f2bf((ob4.z - mi4[2]) * rr[2]), f2bf((ob4.w - mi4[3]) * rr[3]));
  *(ushort4*)(U2b + (size_t)(b * 32 + 16) * 1024 + m0) = od;
  ushort4 z = make_ushort4(0, 0, 0, 0);
#pragma unroll
  for (int jj = 17; jj < 32; ++jj)
    *(ushort4*)(U2b + (size_t)(b * 32 + jj) * 1024 + m0) = z;
}

// ---------------- W2op[b][32][1024] = U2b[b] @ wop^T (MFMA, M=32) ------------
__global__ __launch_bounds__(256)
void w2op_gemm(const u16* __restrict__ U2b, const u16* __restrict__ wop,
               float* __restrict__ W2op) {
  __shared__ u16 sA[32 * 64];
  __shared__ u16 sB[128 * 64];
  const int b = blockIdx.y;
  const int bn0 = blockIdx.x * 128;
  const int tid = threadIdx.x;
  const int w = tid >> 6, l = tid & 63;
  const int lr = l & 15, lk = l >> 4;
  const int swz = lr & 7;
  const int srow = tid >> 3;
  const int scol = ((tid & 7) ^ (srow & 7)) << 3;
  const u16* Ab = U2b + (size_t)b * 32768 + (size_t)srow * 1024 + scol;
  const u16* Bb = wop + (size_t)(bn0 + srow) * 1024 + scol;
  const size_t rstride32 = (size_t)32 * 1024;

  f32x4 acc[2][2] = {};
  for (int k0 = 0; k0 < 1024; k0 += 64) {
    glds16(Ab + k0, sA + w * 512);
#pragma unroll
    for (int p = 0; p < 4; ++p)
      glds16(Bb + p * rstride32 + k0, sB + p * 2048 + w * 512);
    __syncthreads();
#pragma unroll
    for (int ks = 0; ks < 2; ++ks) {
      const int off = (((ks << 2) + lk) ^ swz) << 3;
      bf16x8 af[2], bfr[2];
#pragma unroll
      for (int m = 0; m < 2; ++m)
        af[m] = *(const bf16x8*)(sA + (m * 16 + lr) * 64 + off);
#pragma unroll
      for (int n = 0; n < 2; ++n)
        bfr[n] = *(const bf16x8*)(sB + (w * 32 + n * 16 + lr) * 64 + off);
#pragma unroll
      for (int m = 0; m < 2; ++m)
#pragma unroll
        for (int n = 0; n < 2; ++n)
          acc[m][n] = __builtin_amdgcn_mfma_f32_16x16x32_bf16(af[m], bfr[n], acc[m][n], 0, 0, 0);
    }
    __syncthreads();
  }
#pragma unroll
  for (int m = 0; m < 2; ++m)
#pragma unroll
    for (int n = 0; n < 2; ++n)
#pragma unroll
      for (int i = 0; i < 4; ++i) {
        const int row = m * 16 + lk * 4 + i;
        const int col = bn0 + w * 32 + n * 16 + lr;
        W2op[((size_t)b * 32 + row) * 1024 + col] = acc[m][n][i];
      }
}

// ---------------- analytic BN stats of Z (partials over b-groups) ------------
__global__ __launch_bounds__(256)
void znstats_part(const float* __restrict__ W2op, const float* __restrict__ G,
                  const float* __restrict__ pbar, float* __restrict__ pmu,
                  float* __restrict__ pe2) {
  __shared__ float Gs[256], pb[16];
  const int m = blockIdx.x * 256 + threadIdx.x;
  const int bg = blockIdx.y;
  float amu = 0.f, ae2 = 0.f;
  for (int bi = 0; bi < 4; ++bi) {
    const int b = bg * 4 + bi;
    __syncthreads();
    Gs[threadIdx.x] = G[b * 256 + threadIdx.x];
    if (threadIdx.x < 16) pb[threadIdx.x] = pbar[b * 16 + threadIdx.x];
    __syncthreads();
    float wv[17];
#pragma unroll
    for (int jj = 0; jj < 17; ++jj) wv[jj] = W2op[((size_t)b * 32 + jj) * 1024 + m];
    float s1 = 0.f;
#pragma unroll
    for (int jj = 0; jj < 16; ++jj) s1 += pb[jj] * wv[jj];
    float q = 0.f;
#pragma unroll
    for (int jj = 0; jj < 16; ++jj) {
      float gq = 0.f;
#pragma unroll
      for (int j2 = 0; j2 < 16; ++j2) gq += Gs[jj * 16 + j2] * wv[j2];
      q += wv[jj] * gq;
    }
    const float cz = wv[16];
    amu += s1 + cz;
    ae2 += q + 2.f * cz * s1 + cz * cz;
  }
  pmu[bg * 1024 + m] = amu;
  pe2[bg * 1024 + m] = ae2;
}

__global__ __launch_bounds__(256)
void znfin(const float* __restrict__ pmu, const float* __restrict__ pe2,
           const float* __restrict__ g, const float* __restrict__ be,
           float* __restrict__ afin, float* __restrict__ cf0) {
  const int m = blockIdx.x * 256 + threadIdx.x;
  float mu = 0.f, e2 = 0.f;
#pragma unroll
  for (int i = 0; i < 8; ++i) { mu += pmu[i * 1024 + m]; e2 += pe2[i * 1024 + m]; }
  mu *= (1.f / 32.f); e2 *= (1.f / 32.f);
  const float var = fmaxf(e2 - mu * mu, 0.f);
  const float A = rsqrtf(var + EPS) * g[m];
  afin[m] = A;
  cf0[m] = be[m] - mu * A;
}

// ---------------- final: out[t,m] = sum_j P[t,j]*W2op[b][j,m]*A[m] + const ---
__global__ __launch_bounds__(256)
void zfinal(const float* __restrict__ P, const float* __restrict__ W2op,
            const float* __restrict__ afin, const float* __restrict__ cf0,
            float* __restrict__ out) {
  __shared__ float PL[512];            // 32 rows x 16 probs
  const int blk = blockIdx.x;          // 1024 blocks
  const int b = blk >> 5;
  const int r0 = blk * 32;             // global row base
  const int tid = threadIdx.x;
  const int col = tid * 4;

  f32x4 A4 = *(const f32x4*)(afin + col);
  f32x4 wreg[17];
#pragma unroll
  for (int jj = 0; jj < 17; ++jj) {
    f32x4 wv = *(const f32x4*)(W2op + ((size_t)b * 32 + jj) * 1024 + col);
    wreg[jj] = wv * A4;
  }
  const f32x4 basev = wreg[16] + *(const f32x4*)(cf0 + col);

  if (tid < 128)
    ((f32x4*)PL)[tid] = *(const f32x4*)(P + (size_t)r0 * 16 + tid * 4);
  __syncthreads();

  float* obase = out + (size_t)r0 * 1024 + col;
  for (int r = 0; r < 32; ++r) {
    const float* pr = PL + r * 16;
    f32x4 a = basev;
#pragma unroll
    for (int jj = 0; jj < 16; ++jj) a += pr[jj] * wreg[jj];
    *(f32x4*)(obase + (size_t)r * 1024) = a;
  }
}

// =============================================================================
extern "C" void kernel_launch(void* const* d_in, const int* in_sizes, int n_in,
                              void* d_out, int out_size, void* d_ws, size_t ws_size,
                              hipStream_t stream) {
  (void)in_sizes; (void)n_in; (void)out_size; (void)ws_size;

  const float* src      = (const float*)d_in[0];
  const float* lan      = (const float*)d_in[1];
  const float* qmask    = (const float*)d_in[3];
  const float* ip_w     = (const float*)d_in[4];
  const float* ip_g     = (const float*)d_in[6];
  const float* ip_beta  = (const float*)d_in[7];
  const float* lp_w     = (const float*)d_in[8];
  const float* lp_b     = (const float*)d_in[9];
  const float* mem_tok  = (const float*)d_in[10];
  const float* neg_tok  = (const float*)d_in[11];
  const float* vl_qw    = (const float*)d_in[12];
  const float* vl_qb    = (const float*)d_in[13];
  const float* vl_kw    = (const float*)d_in[14];
  const float* vl_kb    = (const float*)d_in[15];
  const float* mf_qw    = (const float*)d_in[20];
  const float* mf_qb    = (const float*)d_in[21];
  const float* mf_kw    = (const float*)d_in[22];
  const float* mf_kb    = (const float*)d_in[23];
  const float* mf_vw    = (const float*)d_in[24];
  const float* mf_vb    = (const float*)d_in[25];
  const float* mf_ow    = (const float*)d_in[26];
  const float* mf_ob    = (const float*)d_in[27];
  const float* ff_qw    = (const float*)d_in[28];
  const float* ff_qb    = (const float*)d_in[29];
  const float* ff_kw    = (const float*)d_in[30];
  const float* ff_kb    = (const float*)d_in[31];
  const float* ff_vw    = (const float*)d_in[32];
  const float* ff_vb    = (const float*)d_in[33];
  const float* ff_ow    = (const float*)d_in[34];
  const float* ff_ob    = (const float*)d_in[35];
  const float* op_w     = (const float*)d_in[36];
  const float* op_g     = (const float*)d_in[38];
  const float* op_beta  = (const float*)d_in[39];

  float* out_final = (float*)d_out;
  float* out_cur   = out_final + 33554432ull;
  float* out_vl    = out_cur + 65536ull;
  float* out_mem   = out_vl + 16777216ull;
  float* out_ff    = out_mem + 16384ull;

  // ---- workspace carve ----
  char* wp = (char*)d_ws;
  auto take = [&](size_t sz) { char* r = wp; wp += (sz + 255) & ~(size_t)255; return r; };
  u16*   W1   = (u16*)  take(67108864);    // Q2 (vl q'')
  u16*   W2   = (u16*)  take(67108864);    // Y1 (pre-BN ip output), live to ff_score
  u16*   LP   = (u16*)  take(4194304);     // lan_p bf16
  u16*   QV   = (u16*)  take(4194304);     // vl q bf16
  u16*   KM   = (u16*)  take(4194304);     // mf k bf16
  u16*   VM   = (u16*)  take(4194304);     // mf v bf16
  u16*   LANB = (u16*)  take(3145728);     // lan bf16
  u16*   wip  = (u16*)  take(2097152);
  u16*   wlp  = (u16*)  take(1572864);
  u16*   wvq  = (u16*)  take(2097152);
  u16*   wmk  = (u16*)  take(2097152);
  u16*   wmv  = (u16*)  take(2097152);
  u16*   wop  = (u16*)  take(2097152);     // op_w bf16 [m][c]
  u16*   wmo  = (u16*)  take(2097152);     // mf_ow bf16
  u16*   wfqb = (u16*)  take(2097152);     // ff_qw bf16
  u16*   wfk  = (u16*)  take(2097152);     // ff_kw bf16
  u16*   wfv  = (u16*)  take(2097152);     // ff_vw bf16
  u16*   wvkT = (u16*)  take(2097152);     // vl_kw^T bf16
  u16*   wfoT = (u16*)  take(2097152);     // ff_ow^T bf16
  u16*   w2ff = (u16*)  take(1048576);     // folded ff-q weights [32][16][1024]
  u16*   U2b  = (u16*)  take(2097152);     // [32][32][1024] bf16
  float* qmf   = (float*)take(4096);
  float* attvm = (float*)take(131072);
  float* memo  = (float*)take(131072);
  float* curw  = (float*)take(262144);
  float* kff   = (float*)take(262144);
  float* vff   = (float*)take(262144);
  float* ps    = (float*)take(1048576);    // [256][1024] partials
  float* pq    = (float*)take(1048576);
  float2* st1  = (float2*)take(8192);
  float* afv   = (float*)take(4096);
  float* cfv   = (float*)take(4096);
  float* wcv   = (float*)take(4096);
  float* cff   = (float*)take(2048);
  float* Pbuf  = (float*)take(2097152);    // [32768][16]
  float* Ub    = (float*)take(2097152);    // [32][16][1024]
  float* W2opb = (float*)take(4194304);    // [32][32][1024] f32
  float* Gb    = (float*)take(32768);      // [32][256]
  float* pbarb = (float*)take(2048);       // [32][16]
  float* Gpart = (float*)take(262144);     // [32][8][256]
  float* pbpart= (float*)take(16384);      // [32][8][16]
  float* pmu   = (float*)take(32768);      // [8][1024]
  float* pe2   = (float*)take(32768);      // [8][1024]
  float* afin  = (float*)take(4096);
  float* cf0   = (float*)take(4096);

  const dim3 blk(256);

  // conversions (weights + lan; src conversion fused into gemm_ip)
  {
    F2B12 j;
    const float* ins[11] = {lan, ip_w, lp_w, vl_qw, mf_kw, mf_vw, op_w,
                            mf_ow, ff_qw, ff_kw, ff_vw};
    u16* outs[11] = {LANB, wip, wlp, wvq, wmk, wmv, wop, wmo, wfqb, wfk, wfv};
    int n4s[11] = {393216, 262144, 196608, 262144, 262144, 262144, 262144,
                   262144, 262144, 262144, 262144};
    for (int i = 0; i < 11; ++i) { j.in[i] = ins[i]; j.out[i] = outs[i]; j.n4[i] = n4s[i]; }
    f2b_multi<<<dim3(1024, 11), blk, 0, stream>>>(j);
  }
  {
    WT2 g;
    g.W[0] = vl_kw; g.WT[0] = wvkT;
    g.W[1] = ff_ow; g.WT[1] = wfoT;
    wtrans2<<<dim3(16, 16, 2), blk, 0, stream>>>(g);
  }

  // stage 0: input proj (fused f32->bf16 + fused column stats) -> Y1 (W2)
  gemm_ip<<<dim3(8, 256), blk, 0, stream>>>(src, wip, W2, ps, pq, 32768, 1024, 1024);
  colstats_final<<<dim3(32), blk, 0, stream>>>(ps, pq, st1, ip_g, ip_beta, afv, cfv, 1.0f / 32768.0f);

  // lan proj, then {vl_q, mf_k, mf_v} in one z-batched launch
  gemm_bt<<<dim3(8, 16), blk, 0, stream>>>(LANB, wlp, lp_b, LP, 2048, 1024, 768);
  {
    G3 g;
    g.B[0] = wvq; g.bias[0] = vl_qb; g.C[0] = QV;
    g.B[1] = wmk; g.bias[1] = mf_kb; g.C[1] = KM;
    g.B[2] = wmv; g.bias[2] = mf_vb; g.C[2] = VM;
    gemm_bt_z<<<dim3(8, 16, 3), blk, 0, stream>>>(LP, g, 2048, 1024, 1024);
  }

  // stage 1 (vl, k-proj folded; fused score+softmax v4 w/ in-block cst)
  gemm_qpp<<<dim3(8, 16, 8), blk, 0, stream>>>(QV, wvkT, afv, W1);
  {
    VG2 g;
    g.A[0] = cfv;     g.W[0] = vl_kw; g.bias[0] = vl_kb; g.out[0] = wcv;
    g.A[1] = mem_tok; g.W[1] = mf_qw; g.bias[1] = mf_qb; g.out[1] = qmf;
    vec_gemm2<<<dim3(32, 1, 2), blk, 0, stream>>>(g);
  }
  vl_fused<<<dim3(256), dim3(512), 0, stream>>>(W1, W2, QV, wcv, qmask, out_vl);

  // stage 2 (memory fuse; per-(b,h) attention, bf16 o-proj weight)
  mem_attn<<<dim3(256), blk, 0, stream>>>(qmf, KM, VM, qmask, out_mem, attvm);
  small_gemm_bf<<<dim3(4, 32), blk, 0, stream>>>(attvm, wmo, mf_ob, memo, 1024, 1024);
  make_cur<<<dim3(128), blk, 0, stream>>>(neg_tok, memo, out_cur, curw);

  // stage 3 (feature fuse, fully rank-16 folded; bf16 k/v/q weights)
  {
    SGB2 g;
    g.W[0] = wfk; g.bias[0] = ff_kb; g.out[0] = kff;
    g.W[1] = wfv; g.bias[1] = ff_vb; g.out[1] = vff;
    small_gemm2_bf<<<dim3(4, 64, 2), blk, 0, stream>>>(curw, g, 1024, 1024);
  }
  ffw_fold<<<dim3(16, 32), blk, 0, stream>>>(kff, wfqb, ff_qb, afv, cfv, w2ff, cff);
  ff_score<<<dim3(8, 32), blk, 0, stream>>>(W2, w2ff, cff, Pbuf, out_ff);
  pg_part<<<dim3(32, 8), blk, 0, stream>>>(Pbuf, Gpart, pbpart);
  ufold<<<dim3(16, 32), blk, 0, stream>>>(vff, wfoT, Ub);
  iprep<<<dim3(32), blk, 0, stream>>>(Ub, Gpart, pbpart, ff_ob, U2b, Gb, pbarb);
  w2op_gemm<<<dim3(8, 32), blk, 0, stream>>>(U2b, wop, W2opb);
  znstats_part<<<dim3(4, 8), blk, 0, stream>>>(W2opb, Gb, pbarb, pmu, pe2);
  znfin<<<dim3(4), blk, 0, stream>>>(pmu, pe2, op_g, op_beta, afin, cf0);
  zfinal<<<dim3(1024), blk, 0, stream>>>(Pbuf, W2opb, afin, cf0, out_final);
}